// Round 6
// baseline (3370.819 us; speedup 1.0000x reference)
//
#include <hip/hip_runtime.h>
#include <hip/hip_bf16.h>
#include <math.h>

#define NS    8
#define NNI   32
#define NCI   128
#define NHH   16
#define NWW   16
#define NCO   128
#define NFF   1152
#define NLL   256
#define LAMV  1152.0f
#define COOPG 512

typedef short s8v __attribute__((ext_vector_type(8)));
typedef float f4v __attribute__((ext_vector_type(4)));

#define AS1 __attribute__((address_space(1)))
#define AS3 __attribute__((address_space(3)))

__device__ __forceinline__ float rdl(float v, int l) {
  return __uint_as_float(__builtin_amdgcn_readlane(__float_as_uint(v), (unsigned)l));
}

// intra-wave LDS write->read ordering fence (no cross-wave barrier needed)
#define WAVE_LDS_FENCE() asm volatile("s_waitcnt lgkmcnt(0)" ::: "memory")

// ---------------------------------------------------------------- build Xu (bf16), z-loop inside
__global__ __launch_bounds__(256) void k_build_Xu(const float* __restrict__ X,
                                                  const float* __restrict__ lp,
                                                  unsigned short* __restrict__ Xu,
                                                  int nz) {
  unsigned idx = blockIdx.x * 256u + threadIdx.x;   // < 1152*8192
  unsigned m = idx & 8191u;
  unsigned f = idx >> 13;
  unsigned n = m >> 8, l = m & 255u, h = l >> 4, w = l & 15u;
  unsigned c = f / 9u, a = f - 9u * c;
  unsigned ki = a / 3u, kj = a - 3u * ki;
  int hi = (int)(h + ki) - 1, wi = (int)(w + kj) - 1;
  bool inb = (hi >= 0 && hi < NHH && wi >= 0 && wi < NWW);
  size_t xoff = (((size_t)n * NCI + c) << 8) + (size_t)(unsigned)(hi * NWW + wi);
  float spn = expf(0.5f * lp[n]);
  for (int z = 0; z < nz; ++z) {
    float v = inb ? X[(size_t)z * 1048576 + xoff] : 0.f;
    __hip_bfloat16 hv = __float2bfloat16(spn * v);
    Xu[(size_t)z * (NFF * 8192) + idx] = *(unsigned short*)&hv;
  }
}

__global__ __launch_bounds__(256) void k_build_B(const float* __restrict__ u,
                                                 const float* __restrict__ lp,
                                                 unsigned short* __restrict__ Bm) {
  unsigned idx = blockIdx.x * 256u + threadIdx.x;   // < 1,048,576
  unsigned m = idx & 8191u;
  unsigned c = idx >> 13;
  unsigned n = m >> 8, l = m & 255u;
  float spn = expf(0.5f * lp[n]);
  __hip_bfloat16 hv = __float2bfloat16(spn * u[((size_t)n * NCO + c) * NLL + l]);
  Bm[idx] = *(unsigned short*)&hv;
}

__global__ void k_diag_init(float* __restrict__ prec) {
  int s = blockIdx.y;
  int i = blockIdx.x * 256 + threadIdx.x;
  if (i < NFF) prec[(size_t)s * NFF * NFF + (size_t)i * NFF + i] = LAMV;
}

// ---------------------------------------------------------------- MFMA bf16 GEMM, SB s per launch
__global__ __launch_bounds__(256) void k_mfma(const unsigned short* __restrict__ XuBase,
                                              const unsigned short* __restrict__ Bm,
                                              float* __restrict__ prec,
                                              float* __restrict__ XLY,
                                              int kLen, int direct) {
  __shared__ unsigned short As[8192];
  __shared__ unsigned short Bs[8192];
  int z = blockIdx.z;
  const unsigned short* Xu = XuBase + (size_t)z * (NFF * 8192);
  prec += (size_t)z * NFF * NFF;
  XLY += (size_t)z * NFF * NCO;
  int bx = blockIdx.x;
  int row0, col0;
  const unsigned short* Ag;
  const unsigned short* Bg;
  bool isXLX;
  if (bx < 45) {
    int b = 0;
    while ((b + 1) * (b + 2) / 2 <= bx) b++;
    row0 = b * 128;
    col0 = (bx - b * (b + 1) / 2) * 128;
    Bg = Xu + (size_t)col0 * 8192;
    isXLX = true;
  } else {
    row0 = (bx - 45) * 128;
    col0 = 0;
    Bg = Bm;
    isXLX = false;
  }
  Ag = Xu + (size_t)row0 * 8192;

  int t = threadIdx.x;
  int lane = t & 63, w = t >> 6;
  int wm = w & 1, wn = w >> 1;
  int n16 = lane & 15, q = lane >> 4;
  int srow = lane >> 3, sch = lane & 7;

  f4v acc[4][4];
#pragma unroll
  for (int i = 0; i < 4; ++i)
#pragma unroll
    for (int j = 0; j < 4; ++j) acc[i][j] = (f4v)0.f;

  int kBase = blockIdx.y * kLen;
  for (int k0 = kBase; k0 < kBase + kLen; k0 += 64) {
    __syncthreads();
#pragma unroll
    for (int it = 0; it < 4; ++it) {
      int rA = (w * 4 + it) * 8 + srow;
      int cA = (sch - rA) & 7;
      const unsigned short* gpa = Ag + (size_t)rA * 8192 + k0 + cA * 8;
      const unsigned short* gpb = Bg + (size_t)rA * 8192 + k0 + cA * 8;
      __builtin_amdgcn_global_load_lds((AS1 const void*)gpa,
                                       (AS3 void*)&As[(w * 4 + it) * 512], 16, 0, 0);
      __builtin_amdgcn_global_load_lds((AS1 const void*)gpb,
                                       (AS3 void*)&Bs[(w * 4 + it) * 512], 16, 0, 0);
    }
    __syncthreads();
#pragma unroll
    for (int kk = 0; kk < 2; ++kk) {
      s8v af[4], bf[4];
#pragma unroll
      for (int im = 0; im < 4; ++im) {
        int r = wm * 64 + im * 16 + n16;
        int slot = ((kk * 4 + q) + r) & 7;
        af[im] = *(const s8v*)&As[r * 64 + slot * 8];
      }
#pragma unroll
      for (int in = 0; in < 4; ++in) {
        int r = wn * 64 + in * 16 + n16;
        int slot = ((kk * 4 + q) + r) & 7;
        bf[in] = *(const s8v*)&Bs[r * 64 + slot * 8];
      }
#pragma unroll
      for (int im = 0; im < 4; ++im)
#pragma unroll
        for (int in = 0; in < 4; ++in)
          acc[im][in] = __builtin_amdgcn_mfma_f32_16x16x32_bf16(af[im], bf[in], acc[im][in], 0, 0, 0);
    }
  }

#pragma unroll
  for (int im = 0; im < 4; ++im)
#pragma unroll
    for (int in = 0; in < 4; ++in) {
      int gr = row0 + wm * 64 + im * 16 + q * 4;
      int gc = (isXLX ? col0 : 0) + wn * 64 + in * 16 + n16;
      if (direct) {
        if (isXLX) {
#pragma unroll
          for (int tt = 0; tt < 4; ++tt)
            prec[(size_t)(gr + tt) * NFF + gc] =
                acc[im][in][tt] + ((gr + tt) == gc ? LAMV : 0.f);
        } else {
#pragma unroll
          for (int tt = 0; tt < 4; ++tt)
            XLY[(size_t)(gr + tt) * NCO + gc] = acc[im][in][tt];
        }
      } else {
        if (isXLX) {
#pragma unroll
          for (int tt = 0; tt < 4; ++tt)
            atomicAdd(&prec[(size_t)(gr + tt) * NFF + gc], acc[im][in][tt]);
        } else {
#pragma unroll
          for (int tt = 0; tt < 4; ++tt)
            atomicAdd(&XLY[(size_t)(gr + tt) * NCO + gc], acc[im][in][tt]);
        }
      }
    }
}

// ================================================================ persistent fused kernel
// XCD-local barrier: blocks of one physical XCD (same L2) sync via slot stores + leader scan.
// Data visibility within an XCD: vL1 is write-through (stores reach shared L2 after the
// vmcnt drain in __syncthreads); consumers only need a vL1 invalidate (buffer_inv, CU-local).
// NO L2 writeback/invalidate anywhere in the main loop.
__device__ __forceinline__ void xsync(unsigned* slot, unsigned* go, unsigned role,
                                      unsigned cnt, unsigned ep) {
  __syncthreads();   // drains vmcnt: all block stores are in the XCD's L2
  int t = threadIdx.x;
  if (t == 0)
    __hip_atomic_store(&slot[role], ep, __ATOMIC_RELAXED, __HIP_MEMORY_SCOPE_AGENT);
  if (role == 0) {
    if (t < 64) {
      for (;;) {
        unsigned ok = 1;
        for (unsigned i = (unsigned)t; i < cnt; i += 64u)
          ok &= (__hip_atomic_load(&slot[i], __ATOMIC_RELAXED, __HIP_MEMORY_SCOPE_AGENT) >= ep)
                    ? 1u : 0u;
        if (__all((int)ok)) break;
        __builtin_amdgcn_s_sleep(2);
      }
      if (t == 0)
        __hip_atomic_store(go, ep, __ATOMIC_RELAXED, __HIP_MEMORY_SCOPE_AGENT);
    }
  } else if (t == 0) {
    while (__hip_atomic_load(go, __ATOMIC_RELAXED, __HIP_MEMORY_SCOPE_AGENT) < ep)
      __builtin_amdgcn_s_sleep(2);
  }
  __syncthreads();
  asm volatile("buffer_inv" ::: "memory");   // vL1 invalidate (CU-local, cheap)
  __syncthreads();
}

// ---- factor 64x64 diag block in global memory (one wave), logdet -> accum_ld
__device__ void dev_fact64(float* D, float* accum_ld, int lane) {
  float x[64];
#pragma unroll
  for (int k = 0; k < 64; ++k) x[k] = D[(size_t)lane * NFF + k];
  float ld = 0.f;
#pragma unroll
  for (int k = 0; k < 64; ++k) {
    float dk = sqrtf(rdl(x[k], k));
    float inv = 1.0f / dk;
    ld += logf(dk);
    x[k] = (lane == k) ? dk : ((lane > k) ? x[k] * inv : x[k]);
#pragma unroll
    for (int kk = k + 1; kk < 64; ++kk)
      x[kk] = fmaf(-x[k], rdl(x[k], kk), x[kk]);
  }
  if (lane == 0) atomicAdd(accum_ld, 2.f * ld);
#pragma unroll
  for (int k = 0; k < 64; ++k) D[(size_t)lane * NFF + k] = x[k];
}

// ---- panel solve X * L_pp^T = A(i,p), one wave; writes lower (i,p) + upper copy (p,i)
__device__ void dev_panel(float* Ps, int p, int i, float* smw) {
  float (*Xs)[66] = (float(*)[66])smw;
  const float* Dp = Ps + (size_t)(p * 64) * NFF + p * 64;
  float* Ai = Ps + (size_t)(i * 64) * NFF + p * 64;
  float* At = Ps + (size_t)(p * 64) * NFF + i * 64;
  int lane = threadIdx.x & 63;
  float Lc[64];
#pragma unroll
  for (int k = 0; k < 64; ++k) Lc[k] = Dp[(size_t)k * NFF + lane];
  for (int r = 0; r < 64; ++r) Xs[r][lane] = Ai[(size_t)r * NFF + lane];
  WAVE_LDS_FENCE();
  float x[64];
#pragma unroll
  for (int k = 0; k < 64; ++k) x[k] = Xs[lane][k];
#pragma unroll
  for (int j = 0; j < 64; ++j) {
    float xj = x[j] / rdl(Lc[j], j);
    x[j] = xj;
#pragma unroll
    for (int k = j + 1; k < 64; ++k)
      x[k] = fmaf(-xj, rdl(Lc[k], j), x[k]);
  }
#pragma unroll
  for (int k = 0; k < 64; ++k) Xs[lane][k] = x[k];
  WAVE_LDS_FENCE();
  for (int r = 0; r < 64; ++r) Ai[(size_t)r * NFF + lane] = Xs[r][lane];
  for (int r = 0; r < 64; ++r) At[(size_t)r * NFF + lane] = Xs[lane][r];
}

// ---- trailing update C(i,j) -= P_i P_j^T; (0,0) tile also factors next diag
__device__ void dev_trail(float* Ps, float* accum, int p, int idx, float* sm) {
  int b = 0;
  while ((b + 1) * (b + 2) / 2 <= idx) b++;
  int c = idx - b * (b + 1) / 2;
  int i = p + 1 + b, j = p + 1 + c;
  const float* Ui = Ps + (size_t)(p * 64) * NFF + i * 64;
  const float* Uj = Ps + (size_t)(p * 64) * NFF + j * 64;
  float* Cb = Ps + (size_t)(i * 64) * NFF + j * 64;
  float (*Ak)[68] = (float(*)[68])sm;
  float (*Bk)[68] = (float(*)[68])(sm + 4352);
  int t = threadIdx.x, tx = t & 15, ty = t >> 4;
  __syncthreads();                    // LDS reuse across task-loop iterations
  for (int e = t; e < 1024; e += 256) {
    int k = e >> 4, c4 = (e & 15) * 4;
    *(float4*)&Ak[k][c4] = *(const float4*)(Ui + (size_t)k * NFF + c4);
    *(float4*)&Bk[k][c4] = *(const float4*)(Uj + (size_t)k * NFF + c4);
  }
  __syncthreads();
  float acc[4][4];
#pragma unroll
  for (int a = 0; a < 4; ++a)
#pragma unroll
    for (int b2 = 0; b2 < 4; ++b2) acc[a][b2] = 0.f;
#pragma unroll
  for (int kk = 0; kk < 64; ++kk) {
    float av[4], bv[4];
    *(float4*)&av[0] = *(const float4*)&Ak[kk][ty * 4];
    *(float4*)&bv[0] = *(const float4*)&Bk[kk][tx * 4];
#pragma unroll
    for (int a = 0; a < 4; ++a)
#pragma unroll
      for (int b2 = 0; b2 < 4; ++b2) acc[a][b2] = fmaf(av[a], bv[b2], acc[a][b2]);
  }
  if (!(b == 0 && c == 0)) {
#pragma unroll
    for (int a = 0; a < 4; ++a) {
      float4* cp = (float4*)(Cb + (size_t)(ty * 4 + a) * NFF + tx * 4);
      float4 cv = *cp;
      cv.x -= acc[a][0]; cv.y -= acc[a][1]; cv.z -= acc[a][2]; cv.w -= acc[a][3];
      *cp = cv;
    }
  } else {
    __syncthreads();
#pragma unroll
    for (int a = 0; a < 4; ++a) {
      float4 cv = *(const float4*)(Cb + (size_t)(ty * 4 + a) * NFF + tx * 4);
      cv.x -= acc[a][0]; cv.y -= acc[a][1]; cv.z -= acc[a][2]; cv.w -= acc[a][3];
      *(float4*)&Ak[ty * 4 + a][tx * 4] = cv;
    }
    __syncthreads();
    if (t < 64) {
      int lane = t;
      float x[64];
#pragma unroll
      for (int k = 0; k < 64; ++k) x[k] = Ak[lane][k];
      float ld = 0.f;
#pragma unroll
      for (int k = 0; k < 64; ++k) {
        float dk = sqrtf(rdl(x[k], k));
        float inv = 1.0f / dk;
        ld += logf(dk);
        x[k] = (lane == k) ? dk : ((lane > k) ? x[k] * inv : x[k]);
#pragma unroll
        for (int kk = k + 1; kk < 64; ++kk)
          x[kk] = fmaf(-x[k], rdl(x[k], kk), x[kk]);
      }
      if (lane == 0) atomicAdd(accum, 2.f * ld);
#pragma unroll
      for (int k = 0; k < 64; ++k) Ak[lane][k] = x[k];
    }
    __syncthreads();
    for (int e = t; e < 1024; e += 256) {
      int r = e >> 4, c4 = (e & 15) * 4;
      *(float4*)(Cb + (size_t)r * NFF + c4) = *(float4*)&Ak[r][c4];
    }
  }
}

// ---- inverse of diag block (one wave): lane j holds column j of Linv
__device__ void dev_invdiag(const float* Ps, float* Ws, int lane) {
  float Lr[64];
#pragma unroll
  for (int m = 0; m < 64; ++m) Lr[m] = Ps[(size_t)lane * NFF + m];
  float x[64];
#pragma unroll
  for (int k = 0; k < 64; ++k) {
    float v = (lane == k) ? 1.f : 0.f;
#pragma unroll
    for (int m = 0; m < k; ++m)
      v = fmaf(-rdl(Lr[m], k), x[m], v);
    x[k] = v / rdl(Lr[k], k);
  }
#pragma unroll
  for (int k = 0; k < 64; ++k) Ws[(size_t)k * NFF + lane] = x[k];
}

// ---- level-1 pair inverse: W[2p+1][2p] = -D2 * L21 * D1
__device__ void dev_inv1(const float* Ps, float* Ws, int p, float* sm) {
  int J = 2 * p, I = 2 * p + 1;
  float (*Ak)[65] = (float(*)[65])sm;
  float (*Bk)[65] = (float(*)[65])(sm + 4160);
  float (*Dk)[65] = (float(*)[65])(sm + 8320);
  float (*Tt)[65] = (float(*)[65])(sm + 12480);
  int t = threadIdx.x, tx = t & 15, ty = t >> 4;
  __syncthreads();
  for (int e = t; e < 4096; e += 256) {
    int r = e >> 6, cc = e & 63;
    Ak[r][cc] = Ps[(size_t)(J * 64 + r) * NFF + I * 64 + cc];
    Bk[r][cc] = Ws[(size_t)(J * 64 + r) * NFF + J * 64 + cc];
  }
  {
    int i = t >> 2;
#pragma unroll
    for (int it = 0; it < 4; ++it) {
      int kq = (t & 3) * 4 + it * 16;
      float4 a = *(const float4*)&Ws[(size_t)(I * 64 + i) * NFF + I * 64 + kq];
      Dk[kq + 0][i] = a.x; Dk[kq + 1][i] = a.y; Dk[kq + 2][i] = a.z; Dk[kq + 3][i] = a.w;
    }
  }
  __syncthreads();
  float acc[4][4];
#pragma unroll
  for (int a = 0; a < 4; ++a)
#pragma unroll
    for (int b = 0; b < 4; ++b) acc[a][b] = 0.f;
#pragma unroll 8
  for (int kk = 0; kk < 64; ++kk) {
    float av[4], bv[4];
#pragma unroll
    for (int a = 0; a < 4; ++a) av[a] = Ak[kk][ty * 4 + a];
#pragma unroll
    for (int b = 0; b < 4; ++b) bv[b] = Bk[kk][tx * 4 + b];
#pragma unroll
    for (int a = 0; a < 4; ++a)
#pragma unroll
      for (int b = 0; b < 4; ++b) acc[a][b] = fmaf(av[a], bv[b], acc[a][b]);
  }
#pragma unroll
  for (int a = 0; a < 4; ++a)
#pragma unroll
    for (int b = 0; b < 4; ++b) Tt[ty * 4 + a][tx * 4 + b] = acc[a][b];
  __syncthreads();
  float a2[4][4];
#pragma unroll
  for (int a = 0; a < 4; ++a)
#pragma unroll
    for (int b = 0; b < 4; ++b) a2[a][b] = 0.f;
#pragma unroll 8
  for (int kk = 0; kk < 64; ++kk) {
    float av[4], bv[4];
#pragma unroll
    for (int a = 0; a < 4; ++a) av[a] = Dk[kk][ty * 4 + a];
#pragma unroll
    for (int b = 0; b < 4; ++b) bv[b] = Tt[kk][tx * 4 + b];
#pragma unroll
    for (int a = 0; a < 4; ++a)
#pragma unroll
      for (int b = 0; b < 4; ++b) a2[a][b] = fmaf(av[a], bv[b], a2[a][b]);
  }
#pragma unroll
  for (int a = 0; a < 4; ++a) {
    float4 o;
    o.x = -a2[a][0]; o.y = -a2[a][1]; o.z = -a2[a][2]; o.w = -a2[a][3];
    *(float4*)&Ws[(size_t)(I * 64 + ty * 4 + a) * NFF + J * 64 + tx * 4] = o;
  }
}

// ---- level kernel A: T = L21 * W11 (tile r, col-block c)
__device__ void dev_invA(const float* Ps, const float* Ws, float* Tbs,
                         int n1, int n2, int nc, int c0, int r, int ccb, int pq,
                         float* sm) {
  int ldT = nc * 64;
  int o = pq * 2 * n1;
  int I = o + n1 + r, c = c0 + ccb;
  float* Ts = Tbs + (size_t)pq * (size_t)(n2 * 64) * ldT;
  float (*Aks)[68] = (float(*)[68])sm;
  float (*Bks)[68] = (float(*)[68])(sm + 1088);
  int t = threadIdx.x, tx = t & 15, ty = t >> 4;
  float acc[4][4];
#pragma unroll
  for (int a = 0; a < 4; ++a)
#pragma unroll
    for (int b = 0; b < 4; ++b) acc[a][b] = 0.f;
  for (int kb = c; kb < n1; ++kb) {
    const float* up = Ps + (size_t)((o + kb) * 64) * NFF + I * 64;
    const float* wp = Ws + (size_t)((o + kb) * 64) * NFF + (o + c) * 64;
    for (int k0 = 0; k0 < 64; k0 += 16) {
      float4 a = *(const float4*)(up + (size_t)(k0 + ty) * NFF + tx * 4);
      float4 b = *(const float4*)(wp + (size_t)(k0 + ty) * NFF + tx * 4);
      __syncthreads();
      *(float4*)&Aks[ty][tx * 4] = a;
      *(float4*)&Bks[ty][tx * 4] = b;
      __syncthreads();
#pragma unroll
      for (int kk = 0; kk < 16; ++kk) {
        float av[4], bv[4];
        *(float4*)&av[0] = *(const float4*)&Aks[kk][ty * 4];
        *(float4*)&bv[0] = *(const float4*)&Bks[kk][tx * 4];
#pragma unroll
        for (int a2 = 0; a2 < 4; ++a2)
#pragma unroll
          for (int b2 = 0; b2 < 4; ++b2) acc[a2][b2] = fmaf(av[a2], bv[b2], acc[a2][b2]);
      }
    }
  }
#pragma unroll
  for (int a = 0; a < 4; ++a) {
    float4 v;
    v.x = acc[a][0]; v.y = acc[a][1]; v.z = acc[a][2]; v.w = acc[a][3];
    *(float4*)(Ts + (size_t)(r * 64 + ty * 4 + a) * ldT + ccb * 64 + tx * 4) = v;
  }
}

// ---- level kernel B: W21 = -W22 * T
__device__ void dev_invB(float* Ws, const float* Tbs,
                         int n1, int n2, int nc, int c0, int r, int ccb, int pq,
                         float* sm) {
  int ldT = nc * 64;
  int o = pq * 2 * n1;
  int I = o + n1 + r, c = c0 + ccb;
  const float* Ts = Tbs + (size_t)pq * (size_t)(n2 * 64) * ldT;
  float (*Aks)[68] = (float(*)[68])sm;
  float (*Bks)[68] = (float(*)[68])(sm + 1088);
  int t = threadIdx.x, tx = t & 15, ty = t >> 4;
  float acc[4][4];
#pragma unroll
  for (int a = 0; a < 4; ++a)
#pragma unroll
    for (int b = 0; b < 4; ++b) acc[a][b] = 0.f;
  for (int kb = 0; kb <= r; ++kb) {
    const float* ap = Ws + (size_t)(I * 64) * NFF + (o + n1 + kb) * 64;
    const float* tp = Ts + (size_t)(kb * 64) * ldT + ccb * 64;
    for (int k0 = 0; k0 < 64; k0 += 16) {
      float4 a = *(const float4*)(ap + (size_t)(t >> 2) * NFF + k0 + (t & 3) * 4);
      float4 b = *(const float4*)(tp + (size_t)(k0 + ty) * ldT + tx * 4);
      __syncthreads();
      Aks[(t & 3) * 4 + 0][t >> 2] = a.x;
      Aks[(t & 3) * 4 + 1][t >> 2] = a.y;
      Aks[(t & 3) * 4 + 2][t >> 2] = a.z;
      Aks[(t & 3) * 4 + 3][t >> 2] = a.w;
      *(float4*)&Bks[ty][tx * 4] = b;
      __syncthreads();
#pragma unroll
      for (int kk = 0; kk < 16; ++kk) {
        float av[4], bv[4];
        *(float4*)&av[0] = *(const float4*)&Aks[kk][ty * 4];
        *(float4*)&bv[0] = *(const float4*)&Bks[kk][tx * 4];
#pragma unroll
        for (int a2 = 0; a2 < 4; ++a2)
#pragma unroll
          for (int b2 = 0; b2 < 4; ++b2) acc[a2][b2] = fmaf(av[a2], bv[b2], acc[a2][b2]);
      }
    }
  }
#pragma unroll
  for (int a = 0; a < 4; ++a) {
    float4 v;
    v.x = -acc[a][0]; v.y = -acc[a][1]; v.z = -acc[a][2]; v.w = -acc[a][3];
    *(float4*)&Ws[(size_t)(I * 64 + ty * 4 + a) * NFF + (o + c) * 64 + tx * 4] = v;
  }
}

// ---- apply 1: t1R = W*XLY + Z (+ sum Z^2)
__device__ void dev_app1(const float* Ws, const float* Ys, const float* Zs,
                         float* Os, float* accum, int rb, int ch, int s, float* sm) {
  int r0 = rb * 64, c0 = ch * 64;
  float (*As_)[68] = (float(*)[68])sm;
  float (*Bs_)[68] = (float(*)[68])(sm + 1088);
  float* red = sm + 2176;
  int t = threadIdx.x, tx = t & 15, ty = t >> 4;
  float acc[4][4];
#pragma unroll
  for (int a = 0; a < 4; ++a)
#pragma unroll
    for (int b = 0; b < 4; ++b) acc[a][b] = 0.f;
  int kmax = r0 + 64;
  for (int k0 = 0; k0 < kmax; k0 += 16) {
    float4 a = *(const float4*)(Ws + (size_t)(r0 + (t >> 2)) * NFF + k0 + (t & 3) * 4);
    float4 bb = *(const float4*)(Ys + (size_t)(k0 + (t >> 4)) * NCO + c0 + (t & 15) * 4);
    __syncthreads();
    As_[(t & 3) * 4 + 0][t >> 2] = a.x; As_[(t & 3) * 4 + 1][t >> 2] = a.y;
    As_[(t & 3) * 4 + 2][t >> 2] = a.z; As_[(t & 3) * 4 + 3][t >> 2] = a.w;
    *(float4*)&Bs_[t >> 4][(t & 15) * 4] = bb;
    __syncthreads();
#pragma unroll
    for (int kk = 0; kk < 16; ++kk) {
      float av[4], bv[4];
      *(float4*)&av[0] = *(const float4*)&As_[kk][ty * 4];
      *(float4*)&bv[0] = *(const float4*)&Bs_[kk][tx * 4];
#pragma unroll
      for (int a2 = 0; a2 < 4; ++a2)
#pragma unroll
        for (int b2 = 0; b2 < 4; ++b2) acc[a2][b2] = fmaf(av[a2], bv[b2], acc[a2][b2]);
    }
  }
  float z2 = 0.f;
#pragma unroll
  for (int a2 = 0; a2 < 4; ++a2) {
    int row = r0 + ty * 4 + a2;
    const float* zp = Zs + (size_t)row * NCO + c0 + tx * 4;
    float* op = Os + (size_t)row * NCO + c0 + tx * 4;
    float4 z0 = *(const float4*)zp;
    float4 v0;
    v0.x = acc[a2][0] + z0.x; v0.y = acc[a2][1] + z0.y;
    v0.z = acc[a2][2] + z0.z; v0.w = acc[a2][3] + z0.w;
    z2 += z0.x * z0.x + z0.y * z0.y + z0.z * z0.z + z0.w * z0.w;
    *(float4*)op = v0;
  }
  __syncthreads();
  red[t] = z2;
  __syncthreads();
  for (int o = 128; o > 0; o >>= 1) {
    if (t < o) red[t] += red[t + o];
    __syncthreads();
  }
  if (t == 0) atomicAdd(&accum[s * 4 + 1], red[0]);
}

// ---- apply 2: sample = W^T * t1R (+ sum S^2)
__device__ void dev_app2(const float* Ws, const float* Rs, float* Op,
                         float* accum, int rb, int ch, int s, float* sm) {
  int r0 = rb * 64, c0 = ch * 64;
  float (*As_)[68] = (float(*)[68])sm;
  float (*Bs_)[68] = (float(*)[68])(sm + 1088);
  float* red = sm + 2176;
  int t = threadIdx.x, tx = t & 15, ty = t >> 4;
  float acc[4][4];
#pragma unroll
  for (int a = 0; a < 4; ++a)
#pragma unroll
    for (int b = 0; b < 4; ++b) acc[a][b] = 0.f;
  for (int k0 = r0; k0 < NFF; k0 += 16) {
    float4 a = *(const float4*)(Ws + (size_t)(k0 + (t >> 4)) * NFF + r0 + (t & 15) * 4);
    float4 bb = *(const float4*)(Rs + (size_t)(k0 + (t >> 4)) * NCO + c0 + (t & 15) * 4);
    __syncthreads();
    *(float4*)&As_[t >> 4][(t & 15) * 4] = a;
    *(float4*)&Bs_[t >> 4][(t & 15) * 4] = bb;
    __syncthreads();
#pragma unroll
    for (int kk = 0; kk < 16; ++kk) {
      float av[4], bv[4];
      *(float4*)&av[0] = *(const float4*)&As_[kk][ty * 4];
      *(float4*)&bv[0] = *(const float4*)&Bs_[kk][tx * 4];
#pragma unroll
      for (int a2 = 0; a2 < 4; ++a2)
#pragma unroll
        for (int b2 = 0; b2 < 4; ++b2) acc[a2][b2] = fmaf(av[a2], bv[b2], acc[a2][b2]);
    }
  }
  float s2 = 0.f;
#pragma unroll
  for (int b2 = 0; b2 < 4; ++b2) {
    int col = c0 + tx * 4 + b2;
    float4 v;
    v.x = acc[0][b2]; v.y = acc[1][b2]; v.z = acc[2][b2]; v.w = acc[3][b2];
    s2 += v.x * v.x + v.y * v.y + v.z * v.z + v.w * v.w;
    *(float4*)(Op + (size_t)col * NFF + r0 + ty * 4) = v;
  }
  __syncthreads();
  red[t] = s2;
  __syncthreads();
  for (int o = 128; o > 0; o >>= 1) {
    if (t < o) red[t] += red[t + o];
    __syncthreads();
  }
  if (t == 0) atomicAdd(&accum[s * 4 + 0], red[0]);
}

// ---- the fused persistent kernel: per-XCD sample pipelines, XCD-local sync
__global__ __launch_bounds__(256, 2) void k_coop(float* __restrict__ prec,
                                                 float* __restrict__ W,
                                                 const float* __restrict__ XLY,
                                                 float* __restrict__ t1R,
                                                 const float* __restrict__ Z,
                                                 float* __restrict__ out,
                                                 float* __restrict__ accum,
                                                 unsigned* __restrict__ syncmem) {
  __shared__ float SM[16896];   // 66 KB: max(panel 4*64*66, trail 2*64*68, inv1 4*64*65)
  __shared__ unsigned shr[2];
  int t = threadIdx.x;
  int wv = t >> 6, lane = t & 63;

  // ---- registration: physical XCD id -> group; role within group
  unsigned xcd;
  asm("s_getreg_b32 %0, hwreg(HW_REG_XCC_ID)" : "=s"(xcd));
  xcd &= 7u;
  unsigned* regcnt = syncmem;              // [0..8)
  unsigned* garr = syncmem + 8;            // [8]
  unsigned* go = syncmem + 64 + xcd * 16;  // padded per-XCD go word
  unsigned* slot = syncmem + 256 + xcd * 512;
  if (t == 0) {
    unsigned r = __hip_atomic_fetch_add(&regcnt[xcd], 1u,
                                        __ATOMIC_RELAXED, __HIP_MEMORY_SCOPE_AGENT);
    asm volatile("s_waitcnt vmcnt(0)" ::: "memory");   // regcnt RMW applied before arrive
    __hip_atomic_fetch_add(garr, 1u, __ATOMIC_RELAXED, __HIP_MEMORY_SCOPE_AGENT);
    while (__hip_atomic_load(garr, __ATOMIC_RELAXED, __HIP_MEMORY_SCOPE_AGENT) < gridDim.x)
      __builtin_amdgcn_s_sleep(8);
    shr[0] = r;
    shr[1] = __hip_atomic_load(&regcnt[xcd], __ATOMIC_RELAXED, __HIP_MEMORY_SCOPE_AGENT);
  }
  __syncthreads();
  unsigned role = shr[0], cnt = shr[1];

  int s = (int)xcd;                         // sample pinned to this XCD
  float* Ps = prec + (size_t)s * NFF * NFF;
  float* Wsb = W + (size_t)s * NFF * NFF;
  const float* Ys = XLY + (size_t)s * 147456;
  float* Rs = t1R + (size_t)s * 147456;
  const float* Zs = Z + (size_t)s * 147456;
  float* Outp = out + (size_t)s * 147456;
  unsigned ep = 0;
#define GS() xsync(slot, go, role, cnt, ++ep)

  // ---- phase 0: factor diag block 0 (1 wave task per sample)
  if (role == 0 && wv == 0) dev_fact64(Ps, &accum[s * 4 + 2], lane);
  GS();

  // ---- 17 cholesky steps: panels then trailing(+fused next diag)
  for (int p = 0; p < 17; ++p) {
    int m = 17 - p;
    for (unsigned tau = role * 4 + wv; tau < (unsigned)m; tau += cnt * 4)
      dev_panel(Ps, p, p + 1 + (int)tau, SM + wv * 4224);
    GS();
    unsigned nt = (unsigned)(m * (m + 1) / 2);
    for (unsigned tau = role; tau < nt; tau += cnt)
      dev_trail(Ps, &accum[s * 4 + 2], p, (int)tau, SM);
    GS();
  }

  // ---- inverse diag blocks (18 wave tasks per sample)
  for (unsigned tau = role * 4 + wv; tau < 18u; tau += cnt * 4) {
    const float* Pd = Ps + (size_t)(tau * 64) * NFF + tau * 64;
    float* Wd = Wsb + (size_t)(tau * 64) * NFF + tau * 64;
    dev_invdiag(Pd, Wd, lane);
  }
  GS();

  // ---- level-1 pair inverse (9 block tasks per sample)
  for (unsigned tau = role; tau < 9u; tau += cnt)
    dev_inv1(Ps, Wsb, (int)tau, SM);
  GS();

  // ---- recursive block-doubling levels: (n1, n2, nc, c0), npairs
  {
    const int LV[5][4] = { {2, 2, 2, 0}, {4, 4, 4, 0},
                           {8, 8, 4, 0}, {8, 8, 4, 4}, {16, 2, 16, 0} };
    const int NP[5] = {4, 2, 1, 1, 1};
    for (int lv = 0; lv < 5; ++lv) {
      int n1 = LV[lv][0], n2 = LV[lv][1], nc = LV[lv][2], c0 = LV[lv][3], np = NP[lv];
      unsigned ntask = (unsigned)(n2 * nc * np);
      for (unsigned tau = role; tau < ntask; tau += cnt) {
        unsigned q = tau;
        int r = (int)(q % (unsigned)n2); q /= (unsigned)n2;
        int ccb = (int)(q % (unsigned)nc); int pq = (int)(q / (unsigned)nc);
        dev_invA(Ps, Wsb, Rs, n1, n2, nc, c0, r, ccb, pq, SM);
      }
      GS();
      for (unsigned tau = role; tau < ntask; tau += cnt) {
        unsigned q = tau;
        int r = (int)(q % (unsigned)n2); q /= (unsigned)n2;
        int ccb = (int)(q % (unsigned)nc); int pq = (int)(q / (unsigned)nc);
        dev_invB(Wsb, Rs, n1, n2, nc, c0, r, ccb, pq, SM);
      }
      GS();
    }
  }

  // ---- apply 1 (36 block tasks per sample)
  for (unsigned tau = role; tau < 36u; tau += cnt) {
    int ch = (int)(tau & 1u), rb = (int)(tau >> 1);
    dev_app1(Wsb, Ys, Zs, Rs, accum, rb, ch, s, SM);
  }
  GS();
  // ---- apply 2 (36 block tasks per sample)
  for (unsigned tau = role; tau < 36u; tau += cnt) {
    int ch = (int)(tau & 1u), rb = (int)(tau >> 1);
    dev_app2(Wsb, Rs, Outp, accum, rb, ch, s, SM);
  }
  GS();
  // ---- final logpq (per-sample, by its XCD's role-0 block)
  if (role == 0 && t == 0) {
    float s2 = __hip_atomic_load(&accum[s * 4 + 0], __ATOMIC_RELAXED, __HIP_MEMORY_SCOPE_AGENT);
    float z2 = __hip_atomic_load(&accum[s * 4 + 1], __ATOMIC_RELAXED, __HIP_MEMORY_SCOPE_AGENT);
    float ld = __hip_atomic_load(&accum[s * 4 + 2], __ATOMIC_RELAXED, __HIP_MEMORY_SCOPE_AGENT);
    float logP = -0.5f * LAMV * s2 + 0.5f * (float)(NCO * NFF) * logf(LAMV);
    float logQ = -0.5f * z2 + 0.5f * (float)NCO * ld;
    out[(size_t)NS * 147456 + s] = logP - logQ;
  }
#undef GS
}

// ---------------------------------------------------------------- launch
extern "C" void kernel_launch(void* const* d_in, const int* in_sizes, int n_in,
                              void* d_out, int out_size, void* d_ws, size_t ws_size,
                              hipStream_t stream) {
  const float* X = (const float*)d_in[0];
  const float* u = (const float*)d_in[1];
  const float* lp = (const float*)d_in[2];
  const float* Z = (const float*)d_in[3];
  float* out = (float*)d_out;

  const size_t XU2 = 18874368;   // 1152*8192*2 (bf16), one s
  const size_t BM2 = 2097152;    // 128*8192*2
  const size_t FF4 = 5308416;    // 1152*1152*4
  const size_t FC4 = 589824;     // 1152*128*4
  const size_t FC = 147456;      // elems
  const size_t FF = 1327104;     // elems
  const size_t XSTR = 1048576;   // X elems per s

  int SB, kslices;
  if (ws_size >= ((size_t)206 << 20))      { SB = 8; kslices = 1; }
  else if (ws_size >= ((size_t)131 << 20)) { SB = 4; kslices = 2; }
  else                                     { SB = 2; kslices = 4; }

  char* ws = (char*)d_ws;
  size_t reg0 = (size_t)SB * XU2 + BM2;
  if (reg0 < 8 * FF4) reg0 = 8 * FF4;      // W aliases region0 after GEMMs
  unsigned short* Xu = (unsigned short*)ws;
  unsigned short* Bm = (unsigned short*)(ws + (size_t)SB * XU2);
  float* W = (float*)ws;
  size_t off = reg0;
  float* prec = (float*)(ws + off); off += 8 * FF4;
  float* XLY = (float*)(ws + off);  off += 8 * FC4;
  float* t1R = (float*)(ws + off);  off += 8 * FC4;   // also level-T scratch
  float* accum = (float*)(ws + off);
  unsigned* syncmem = (unsigned*)(ws + off + 512);    // regcnt/garr/go/slots

  k_build_B<<<4096, 256, 0, stream>>>(u, lp, Bm);
  hipMemsetAsync(accum, 0, 512 + 20480, stream);      // accum + sync region (per launch)
  if (kslices > 1) {
    hipMemsetAsync(prec, 0, 8 * FF4, stream);
    hipMemsetAsync(XLY, 0, 8 * FC4, stream);
    k_diag_init<<<dim3(5, 8), 256, 0, stream>>>(prec);
  }

  for (int pr = 0; pr < 8 / SB; ++pr) {
    k_build_Xu<<<36864, 256, 0, stream>>>(X + (size_t)pr * SB * XSTR, lp, Xu, SB);
    k_mfma<<<dim3(54, kslices, SB), 256, 0, stream>>>(Xu, Bm,
                                                      prec + (size_t)pr * SB * FF,
                                                      XLY + (size_t)pr * SB * FC,
                                                      8192 / kslices, kslices == 1 ? 1 : 0);
  }

  // fused: per-XCD sample pipelines (cholesky + inverse + apply + logpq)
  k_coop<<<COOPG, 256, 0, stream>>>(prec, W, XLY, t1R, Z, out, accum, syncmem);
}

// Round 7
// 1741.273 us; speedup vs baseline: 1.9358x; 1.9358x over previous
//
#include <hip/hip_runtime.h>
#include <hip/hip_bf16.h>
#include <math.h>

#define NS    8
#define NNI   32
#define NCI   128
#define NHH   16
#define NWW   16
#define NCO   128
#define NFF   1152
#define NLL   256
#define LAMV  1152.0f
#define COOPG 512

typedef short s8v __attribute__((ext_vector_type(8)));
typedef float f4v __attribute__((ext_vector_type(4)));

#define AS1 __attribute__((address_space(1)))
#define AS3 __attribute__((address_space(3)))

__device__ __forceinline__ float rdl(float v, int l) {
  return __uint_as_float(__builtin_amdgcn_readlane(__float_as_uint(v), (unsigned)l));
}

// intra-wave LDS write->read ordering fence (no cross-wave barrier needed)
#define WAVE_LDS_FENCE() asm volatile("s_waitcnt lgkmcnt(0)" ::: "memory")

// ---------------------------------------------------------------- build Xu (bf16), z-loop inside
__global__ __launch_bounds__(256) void k_build_Xu(const float* __restrict__ X,
                                                  const float* __restrict__ lp,
                                                  unsigned short* __restrict__ Xu,
                                                  int nz) {
  unsigned idx = blockIdx.x * 256u + threadIdx.x;   // < 1152*8192
  unsigned m = idx & 8191u;
  unsigned f = idx >> 13;
  unsigned n = m >> 8, l = m & 255u, h = l >> 4, w = l & 15u;
  unsigned c = f / 9u, a = f - 9u * c;
  unsigned ki = a / 3u, kj = a - 3u * ki;
  int hi = (int)(h + ki) - 1, wi = (int)(w + kj) - 1;
  bool inb = (hi >= 0 && hi < NHH && wi >= 0 && wi < NWW);
  size_t xoff = (((size_t)n * NCI + c) << 8) + (size_t)(unsigned)(hi * NWW + wi);
  float spn = expf(0.5f * lp[n]);
  for (int z = 0; z < nz; ++z) {
    float v = inb ? X[(size_t)z * 1048576 + xoff] : 0.f;
    __hip_bfloat16 hv = __float2bfloat16(spn * v);
    Xu[(size_t)z * (NFF * 8192) + idx] = *(unsigned short*)&hv;
  }
}

__global__ __launch_bounds__(256) void k_build_B(const float* __restrict__ u,
                                                 const float* __restrict__ lp,
                                                 unsigned short* __restrict__ Bm) {
  unsigned idx = blockIdx.x * 256u + threadIdx.x;   // < 1,048,576
  unsigned m = idx & 8191u;
  unsigned c = idx >> 13;
  unsigned n = m >> 8, l = m & 255u;
  float spn = expf(0.5f * lp[n]);
  __hip_bfloat16 hv = __float2bfloat16(spn * u[((size_t)n * NCO + c) * NLL + l]);
  Bm[idx] = *(unsigned short*)&hv;
}

__global__ void k_diag_init(float* __restrict__ prec) {
  int s = blockIdx.y;
  int i = blockIdx.x * 256 + threadIdx.x;
  if (i < NFF) prec[(size_t)s * NFF * NFF + (size_t)i * NFF + i] = LAMV;
}

// ---------------------------------------------------------------- MFMA bf16 GEMM, SB s per launch
__global__ __launch_bounds__(256) void k_mfma(const unsigned short* __restrict__ XuBase,
                                              const unsigned short* __restrict__ Bm,
                                              float* __restrict__ prec,
                                              float* __restrict__ XLY,
                                              int kLen, int direct) {
  __shared__ unsigned short As[8192];
  __shared__ unsigned short Bs[8192];
  int z = blockIdx.z;
  const unsigned short* Xu = XuBase + (size_t)z * (NFF * 8192);
  prec += (size_t)z * NFF * NFF;
  XLY += (size_t)z * NFF * NCO;
  int bx = blockIdx.x;
  int row0, col0;
  const unsigned short* Ag;
  const unsigned short* Bg;
  bool isXLX;
  if (bx < 45) {
    int b = 0;
    while ((b + 1) * (b + 2) / 2 <= bx) b++;
    row0 = b * 128;
    col0 = (bx - b * (b + 1) / 2) * 128;
    Bg = Xu + (size_t)col0 * 8192;
    isXLX = true;
  } else {
    row0 = (bx - 45) * 128;
    col0 = 0;
    Bg = Bm;
    isXLX = false;
  }
  Ag = Xu + (size_t)row0 * 8192;

  int t = threadIdx.x;
  int lane = t & 63, w = t >> 6;
  int wm = w & 1, wn = w >> 1;
  int n16 = lane & 15, q = lane >> 4;
  int srow = lane >> 3, sch = lane & 7;

  f4v acc[4][4];
#pragma unroll
  for (int i = 0; i < 4; ++i)
#pragma unroll
    for (int j = 0; j < 4; ++j) acc[i][j] = (f4v)0.f;

  int kBase = blockIdx.y * kLen;
  for (int k0 = kBase; k0 < kBase + kLen; k0 += 64) {
    __syncthreads();
#pragma unroll
    for (int it = 0; it < 4; ++it) {
      int rA = (w * 4 + it) * 8 + srow;
      int cA = (sch - rA) & 7;
      const unsigned short* gpa = Ag + (size_t)rA * 8192 + k0 + cA * 8;
      const unsigned short* gpb = Bg + (size_t)rA * 8192 + k0 + cA * 8;
      __builtin_amdgcn_global_load_lds((AS1 const void*)gpa,
                                       (AS3 void*)&As[(w * 4 + it) * 512], 16, 0, 0);
      __builtin_amdgcn_global_load_lds((AS1 const void*)gpb,
                                       (AS3 void*)&Bs[(w * 4 + it) * 512], 16, 0, 0);
    }
    __syncthreads();
#pragma unroll
    for (int kk = 0; kk < 2; ++kk) {
      s8v af[4], bf[4];
#pragma unroll
      for (int im = 0; im < 4; ++im) {
        int r = wm * 64 + im * 16 + n16;
        int slot = ((kk * 4 + q) + r) & 7;
        af[im] = *(const s8v*)&As[r * 64 + slot * 8];
      }
#pragma unroll
      for (int in = 0; in < 4; ++in) {
        int r = wn * 64 + in * 16 + n16;
        int slot = ((kk * 4 + q) + r) & 7;
        bf[in] = *(const s8v*)&Bs[r * 64 + slot * 8];
      }
#pragma unroll
      for (int im = 0; im < 4; ++im)
#pragma unroll
        for (int in = 0; in < 4; ++in)
          acc[im][in] = __builtin_amdgcn_mfma_f32_16x16x32_bf16(af[im], bf[in], acc[im][in], 0, 0, 0);
    }
  }

#pragma unroll
  for (int im = 0; im < 4; ++im)
#pragma unroll
    for (int in = 0; in < 4; ++in) {
      int gr = row0 + wm * 64 + im * 16 + q * 4;
      int gc = (isXLX ? col0 : 0) + wn * 64 + in * 16 + n16;
      if (direct) {
        if (isXLX) {
#pragma unroll
          for (int tt = 0; tt < 4; ++tt)
            prec[(size_t)(gr + tt) * NFF + gc] =
                acc[im][in][tt] + ((gr + tt) == gc ? LAMV : 0.f);
        } else {
#pragma unroll
          for (int tt = 0; tt < 4; ++tt)
            XLY[(size_t)(gr + tt) * NCO + gc] = acc[im][in][tt];
        }
      } else {
        if (isXLX) {
#pragma unroll
          for (int tt = 0; tt < 4; ++tt)
            atomicAdd(&prec[(size_t)(gr + tt) * NFF + gc], acc[im][in][tt]);
        } else {
#pragma unroll
          for (int tt = 0; tt < 4; ++tt)
            atomicAdd(&XLY[(size_t)(gr + tt) * NCO + gc], acc[im][in][tt]);
        }
      }
    }
}

// ================================================================ persistent fused kernel
// XCD-local barrier (unchanged from round 6). This round's single variable is the chol
// working-set shrink: panels are stored ONLY as transposed-upper copies, so the live set
// (panel row p + trailing lower triangle + diag) stays < 4MB and the trailing RMW traffic
// is L2-captured instead of streaming to HBM.
__device__ __forceinline__ void xsync(unsigned* slot, unsigned* go, unsigned role,
                                      unsigned cnt, unsigned ep) {
  __syncthreads();   // drains vmcnt: all block stores are in the XCD's L2
  int t = threadIdx.x;
  if (t == 0)
    __hip_atomic_store(&slot[role], ep, __ATOMIC_RELAXED, __HIP_MEMORY_SCOPE_AGENT);
  if (role == 0) {
    if (t < 64) {
      for (;;) {
        unsigned ok = 1;
        for (unsigned i = (unsigned)t; i < cnt; i += 64u)
          ok &= (__hip_atomic_load(&slot[i], __ATOMIC_RELAXED, __HIP_MEMORY_SCOPE_AGENT) >= ep)
                    ? 1u : 0u;
        if (__all((int)ok)) break;
        __builtin_amdgcn_s_sleep(2);
      }
      if (t == 0)
        __hip_atomic_store(go, ep, __ATOMIC_RELAXED, __HIP_MEMORY_SCOPE_AGENT);
    }
  } else if (t == 0) {
    while (__hip_atomic_load(go, __ATOMIC_RELAXED, __HIP_MEMORY_SCOPE_AGENT) < ep)
      __builtin_amdgcn_s_sleep(2);
  }
  __syncthreads();
  asm volatile("buffer_inv" ::: "memory");   // vL1 invalidate (CU-local, cheap)
  __syncthreads();
}

// ---- factor 64x64 diag block in global memory (one wave), logdet -> accum_ld
__device__ void dev_fact64(float* D, float* accum_ld, int lane) {
  float x[64];
#pragma unroll
  for (int k = 0; k < 64; ++k) x[k] = D[(size_t)lane * NFF + k];
  float ld = 0.f;
#pragma unroll
  for (int k = 0; k < 64; ++k) {
    float dk = sqrtf(rdl(x[k], k));
    float inv = 1.0f / dk;
    ld += logf(dk);
    x[k] = (lane == k) ? dk : ((lane > k) ? x[k] * inv : x[k]);
#pragma unroll
    for (int kk = k + 1; kk < 64; ++kk)
      x[kk] = fmaf(-x[k], rdl(x[k], kk), x[kk]);
  }
  if (lane == 0) atomicAdd(accum_ld, 2.f * ld);
#pragma unroll
  for (int k = 0; k < 64; ++k) D[(size_t)lane * NFF + k] = x[k];
}

// ---- panel solve X * L_pp^T = A(i,p), one wave; writes ONLY the transposed upper copy
// (p,i). The lower (i,p) slot keeps its pre-solve value — nothing downstream reads it:
// trail/inv1/invA read upper copies, invdiag reads diag blocks. Dropping the lower write
// keeps the chol live set L2-resident (round-7 experiment).
__device__ void dev_panel(float* Ps, int p, int i, float* smw) {
  float (*Xs)[66] = (float(*)[66])smw;
  const float* Dp = Ps + (size_t)(p * 64) * NFF + p * 64;
  float* Ai = Ps + (size_t)(i * 64) * NFF + p * 64;
  float* At = Ps + (size_t)(p * 64) * NFF + i * 64;
  int lane = threadIdx.x & 63;
  float Lc[64];
#pragma unroll
  for (int k = 0; k < 64; ++k) Lc[k] = Dp[(size_t)k * NFF + lane];
  for (int r = 0; r < 64; ++r) Xs[r][lane] = Ai[(size_t)r * NFF + lane];
  WAVE_LDS_FENCE();
  float x[64];
#pragma unroll
  for (int k = 0; k < 64; ++k) x[k] = Xs[lane][k];
#pragma unroll
  for (int j = 0; j < 64; ++j) {
    float xj = x[j] / rdl(Lc[j], j);
    x[j] = xj;
#pragma unroll
    for (int k = j + 1; k < 64; ++k)
      x[k] = fmaf(-xj, rdl(Lc[k], j), x[k]);
  }
#pragma unroll
  for (int k = 0; k < 64; ++k) Xs[lane][k] = x[k];
  WAVE_LDS_FENCE();
  for (int r = 0; r < 64; ++r) At[(size_t)r * NFF + lane] = Xs[lane][r];
}

// ---- trailing update C(i,j) -= P_i P_j^T; (0,0) tile also factors next diag
__device__ void dev_trail(float* Ps, float* accum, int p, int idx, float* sm) {
  int b = 0;
  while ((b + 1) * (b + 2) / 2 <= idx) b++;
  int c = idx - b * (b + 1) / 2;
  int i = p + 1 + b, j = p + 1 + c;
  const float* Ui = Ps + (size_t)(p * 64) * NFF + i * 64;
  const float* Uj = Ps + (size_t)(p * 64) * NFF + j * 64;
  float* Cb = Ps + (size_t)(i * 64) * NFF + j * 64;
  float (*Ak)[68] = (float(*)[68])sm;
  float (*Bk)[68] = (float(*)[68])(sm + 4352);
  int t = threadIdx.x, tx = t & 15, ty = t >> 4;
  __syncthreads();                    // LDS reuse across task-loop iterations
  for (int e = t; e < 1024; e += 256) {
    int k = e >> 4, c4 = (e & 15) * 4;
    *(float4*)&Ak[k][c4] = *(const float4*)(Ui + (size_t)k * NFF + c4);
    *(float4*)&Bk[k][c4] = *(const float4*)(Uj + (size_t)k * NFF + c4);
  }
  __syncthreads();
  float acc[4][4];
#pragma unroll
  for (int a = 0; a < 4; ++a)
#pragma unroll
    for (int b2 = 0; b2 < 4; ++b2) acc[a][b2] = 0.f;
#pragma unroll
  for (int kk = 0; kk < 64; ++kk) {
    float av[4], bv[4];
    *(float4*)&av[0] = *(const float4*)&Ak[kk][ty * 4];
    *(float4*)&bv[0] = *(const float4*)&Bk[kk][tx * 4];
#pragma unroll
    for (int a = 0; a < 4; ++a)
#pragma unroll
      for (int b2 = 0; b2 < 4; ++b2) acc[a][b2] = fmaf(av[a], bv[b2], acc[a][b2]);
  }
  if (!(b == 0 && c == 0)) {
#pragma unroll
    for (int a = 0; a < 4; ++a) {
      float4* cp = (float4*)(Cb + (size_t)(ty * 4 + a) * NFF + tx * 4);
      float4 cv = *cp;
      cv.x -= acc[a][0]; cv.y -= acc[a][1]; cv.z -= acc[a][2]; cv.w -= acc[a][3];
      *cp = cv;
    }
  } else {
    __syncthreads();
#pragma unroll
    for (int a = 0; a < 4; ++a) {
      float4 cv = *(const float4*)(Cb + (size_t)(ty * 4 + a) * NFF + tx * 4);
      cv.x -= acc[a][0]; cv.y -= acc[a][1]; cv.z -= acc[a][2]; cv.w -= acc[a][3];
      *(float4*)&Ak[ty * 4 + a][tx * 4] = cv;
    }
    __syncthreads();
    if (t < 64) {
      int lane = t;
      float x[64];
#pragma unroll
      for (int k = 0; k < 64; ++k) x[k] = Ak[lane][k];
      float ld = 0.f;
#pragma unroll
      for (int k = 0; k < 64; ++k) {
        float dk = sqrtf(rdl(x[k], k));
        float inv = 1.0f / dk;
        ld += logf(dk);
        x[k] = (lane == k) ? dk : ((lane > k) ? x[k] * inv : x[k]);
#pragma unroll
        for (int kk = k + 1; kk < 64; ++kk)
          x[kk] = fmaf(-x[k], rdl(x[k], kk), x[kk]);
      }
      if (lane == 0) atomicAdd(accum, 2.f * ld);
#pragma unroll
      for (int k = 0; k < 64; ++k) Ak[lane][k] = x[k];
    }
    __syncthreads();
    for (int e = t; e < 1024; e += 256) {
      int r = e >> 4, c4 = (e & 15) * 4;
      *(float4*)(Cb + (size_t)r * NFF + c4) = *(float4*)&Ak[r][c4];
    }
  }
}

// ---- inverse of diag block (one wave): lane j holds column j of Linv
__device__ void dev_invdiag(const float* Ps, float* Ws, int lane) {
  float Lr[64];
#pragma unroll
  for (int m = 0; m < 64; ++m) Lr[m] = Ps[(size_t)lane * NFF + m];
  float x[64];
#pragma unroll
  for (int k = 0; k < 64; ++k) {
    float v = (lane == k) ? 1.f : 0.f;
#pragma unroll
    for (int m = 0; m < k; ++m)
      v = fmaf(-rdl(Lr[m], k), x[m], v);
    x[k] = v / rdl(Lr[k], k);
  }
#pragma unroll
  for (int k = 0; k < 64; ++k) Ws[(size_t)k * NFF + lane] = x[k];
}

// ---- level-1 pair inverse: W[2p+1][2p] = -D2 * L21 * D1
__device__ void dev_inv1(const float* Ps, float* Ws, int p, float* sm) {
  int J = 2 * p, I = 2 * p + 1;
  float (*Ak)[65] = (float(*)[65])sm;
  float (*Bk)[65] = (float(*)[65])(sm + 4160);
  float (*Dk)[65] = (float(*)[65])(sm + 8320);
  float (*Tt)[65] = (float(*)[65])(sm + 12480);
  int t = threadIdx.x, tx = t & 15, ty = t >> 4;
  __syncthreads();
  for (int e = t; e < 4096; e += 256) {
    int r = e >> 6, cc = e & 63;
    Ak[r][cc] = Ps[(size_t)(J * 64 + r) * NFF + I * 64 + cc];
    Bk[r][cc] = Ws[(size_t)(J * 64 + r) * NFF + J * 64 + cc];
  }
  {
    int i = t >> 2;
#pragma unroll
    for (int it = 0; it < 4; ++it) {
      int kq = (t & 3) * 4 + it * 16;
      float4 a = *(const float4*)&Ws[(size_t)(I * 64 + i) * NFF + I * 64 + kq];
      Dk[kq + 0][i] = a.x; Dk[kq + 1][i] = a.y; Dk[kq + 2][i] = a.z; Dk[kq + 3][i] = a.w;
    }
  }
  __syncthreads();
  float acc[4][4];
#pragma unroll
  for (int a = 0; a < 4; ++a)
#pragma unroll
    for (int b = 0; b < 4; ++b) acc[a][b] = 0.f;
#pragma unroll 8
  for (int kk = 0; kk < 64; ++kk) {
    float av[4], bv[4];
#pragma unroll
    for (int a = 0; a < 4; ++a) av[a] = Ak[kk][ty * 4 + a];
#pragma unroll
    for (int b = 0; b < 4; ++b) bv[b] = Bk[kk][tx * 4 + b];
#pragma unroll
    for (int a = 0; a < 4; ++a)
#pragma unroll
      for (int b = 0; b < 4; ++b) acc[a][b] = fmaf(av[a], bv[b], acc[a][b]);
  }
#pragma unroll
  for (int a = 0; a < 4; ++a)
#pragma unroll
    for (int b = 0; b < 4; ++b) Tt[ty * 4 + a][tx * 4 + b] = acc[a][b];
  __syncthreads();
  float a2[4][4];
#pragma unroll
  for (int a = 0; a < 4; ++a)
#pragma unroll
    for (int b = 0; b < 4; ++b) a2[a][b] = 0.f;
#pragma unroll 8
  for (int kk = 0; kk < 64; ++kk) {
    float av[4], bv[4];
#pragma unroll
    for (int a = 0; a < 4; ++a) av[a] = Dk[kk][ty * 4 + a];
#pragma unroll
    for (int b = 0; b < 4; ++b) bv[b] = Tt[kk][tx * 4 + b];
#pragma unroll
    for (int a = 0; a < 4; ++a)
#pragma unroll
      for (int b = 0; b < 4; ++b) a2[a][b] = fmaf(av[a], bv[b], a2[a][b]);
  }
#pragma unroll
  for (int a = 0; a < 4; ++a) {
    float4 o;
    o.x = -a2[a][0]; o.y = -a2[a][1]; o.z = -a2[a][2]; o.w = -a2[a][3];
    *(float4*)&Ws[(size_t)(I * 64 + ty * 4 + a) * NFF + J * 64 + tx * 4] = o;
  }
}

// ---- level kernel A: T = L21 * W11 (tile r, col-block c)
__device__ void dev_invA(const float* Ps, const float* Ws, float* Tbs,
                         int n1, int n2, int nc, int c0, int r, int ccb, int pq,
                         float* sm) {
  int ldT = nc * 64;
  int o = pq * 2 * n1;
  int I = o + n1 + r, c = c0 + ccb;
  float* Ts = Tbs + (size_t)pq * (size_t)(n2 * 64) * ldT;
  float (*Aks)[68] = (float(*)[68])sm;
  float (*Bks)[68] = (float(*)[68])(sm + 1088);
  int t = threadIdx.x, tx = t & 15, ty = t >> 4;
  float acc[4][4];
#pragma unroll
  for (int a = 0; a < 4; ++a)
#pragma unroll
    for (int b = 0; b < 4; ++b) acc[a][b] = 0.f;
  for (int kb = c; kb < n1; ++kb) {
    const float* up = Ps + (size_t)((o + kb) * 64) * NFF + I * 64;
    const float* wp = Ws + (size_t)((o + kb) * 64) * NFF + (o + c) * 64;
    for (int k0 = 0; k0 < 64; k0 += 16) {
      float4 a = *(const float4*)(up + (size_t)(k0 + ty) * NFF + tx * 4);
      float4 b = *(const float4*)(wp + (size_t)(k0 + ty) * NFF + tx * 4);
      __syncthreads();
      *(float4*)&Aks[ty][tx * 4] = a;
      *(float4*)&Bks[ty][tx * 4] = b;
      __syncthreads();
#pragma unroll
      for (int kk = 0; kk < 16; ++kk) {
        float av[4], bv[4];
        *(float4*)&av[0] = *(const float4*)&Aks[kk][ty * 4];
        *(float4*)&bv[0] = *(const float4*)&Bks[kk][tx * 4];
#pragma unroll
        for (int a2 = 0; a2 < 4; ++a2)
#pragma unroll
          for (int b2 = 0; b2 < 4; ++b2) acc[a2][b2] = fmaf(av[a2], bv[b2], acc[a2][b2]);
      }
    }
  }
#pragma unroll
  for (int a = 0; a < 4; ++a) {
    float4 v;
    v.x = acc[a][0]; v.y = acc[a][1]; v.z = acc[a][2]; v.w = acc[a][3];
    *(float4*)(Ts + (size_t)(r * 64 + ty * 4 + a) * ldT + ccb * 64 + tx * 4) = v;
  }
}

// ---- level kernel B: W21 = -W22 * T
__device__ void dev_invB(float* Ws, const float* Tbs,
                         int n1, int n2, int nc, int c0, int r, int ccb, int pq,
                         float* sm) {
  int ldT = nc * 64;
  int o = pq * 2 * n1;
  int I = o + n1 + r, c = c0 + ccb;
  const float* Ts = Tbs + (size_t)pq * (size_t)(n2 * 64) * ldT;
  float (*Aks)[68] = (float(*)[68])sm;
  float (*Bks)[68] = (float(*)[68])(sm + 1088);
  int t = threadIdx.x, tx = t & 15, ty = t >> 4;
  float acc[4][4];
#pragma unroll
  for (int a = 0; a < 4; ++a)
#pragma unroll
    for (int b = 0; b < 4; ++b) acc[a][b] = 0.f;
  for (int kb = 0; kb <= r; ++kb) {
    const float* ap = Ws + (size_t)(I * 64) * NFF + (o + n1 + kb) * 64;
    const float* tp = Ts + (size_t)(kb * 64) * ldT + ccb * 64;
    for (int k0 = 0; k0 < 64; k0 += 16) {
      float4 a = *(const float4*)(ap + (size_t)(t >> 2) * NFF + k0 + (t & 3) * 4);
      float4 b = *(const float4*)(tp + (size_t)(k0 + ty) * ldT + tx * 4);
      __syncthreads();
      Aks[(t & 3) * 4 + 0][t >> 2] = a.x;
      Aks[(t & 3) * 4 + 1][t >> 2] = a.y;
      Aks[(t & 3) * 4 + 2][t >> 2] = a.z;
      Aks[(t & 3) * 4 + 3][t >> 2] = a.w;
      *(float4*)&Bks[ty][tx * 4] = b;
      __syncthreads();
#pragma unroll
      for (int kk = 0; kk < 16; ++kk) {
        float av[4], bv[4];
        *(float4*)&av[0] = *(const float4*)&Aks[kk][ty * 4];
        *(float4*)&bv[0] = *(const float4*)&Bks[kk][tx * 4];
#pragma unroll
        for (int a2 = 0; a2 < 4; ++a2)
#pragma unroll
          for (int b2 = 0; b2 < 4; ++b2) acc[a2][b2] = fmaf(av[a2], bv[b2], acc[a2][b2]);
      }
    }
  }
#pragma unroll
  for (int a = 0; a < 4; ++a) {
    float4 v;
    v.x = -acc[a][0]; v.y = -acc[a][1]; v.z = -acc[a][2]; v.w = -acc[a][3];
    *(float4*)&Ws[(size_t)(I * 64 + ty * 4 + a) * NFF + (o + c) * 64 + tx * 4] = v;
  }
}

// ---- apply 1: t1R = W*XLY + Z (+ sum Z^2)
__device__ void dev_app1(const float* Ws, const float* Ys, const float* Zs,
                         float* Os, float* accum, int rb, int ch, int s, float* sm) {
  int r0 = rb * 64, c0 = ch * 64;
  float (*As_)[68] = (float(*)[68])sm;
  float (*Bs_)[68] = (float(*)[68])(sm + 1088);
  float* red = sm + 2176;
  int t = threadIdx.x, tx = t & 15, ty = t >> 4;
  float acc[4][4];
#pragma unroll
  for (int a = 0; a < 4; ++a)
#pragma unroll
    for (int b = 0; b < 4; ++b) acc[a][b] = 0.f;
  int kmax = r0 + 64;
  for (int k0 = 0; k0 < kmax; k0 += 16) {
    float4 a = *(const float4*)(Ws + (size_t)(r0 + (t >> 2)) * NFF + k0 + (t & 3) * 4);
    float4 bb = *(const float4*)(Ys + (size_t)(k0 + (t >> 4)) * NCO + c0 + (t & 15) * 4);
    __syncthreads();
    As_[(t & 3) * 4 + 0][t >> 2] = a.x; As_[(t & 3) * 4 + 1][t >> 2] = a.y;
    As_[(t & 3) * 4 + 2][t >> 2] = a.z; As_[(t & 3) * 4 + 3][t >> 2] = a.w;
    *(float4*)&Bs_[t >> 4][(t & 15) * 4] = bb;
    __syncthreads();
#pragma unroll
    for (int kk = 0; kk < 16; ++kk) {
      float av[4], bv[4];
      *(float4*)&av[0] = *(const float4*)&As_[kk][ty * 4];
      *(float4*)&bv[0] = *(const float4*)&Bs_[kk][tx * 4];
#pragma unroll
      for (int a2 = 0; a2 < 4; ++a2)
#pragma unroll
        for (int b2 = 0; b2 < 4; ++b2) acc[a2][b2] = fmaf(av[a2], bv[b2], acc[a2][b2]);
    }
  }
  float z2 = 0.f;
#pragma unroll
  for (int a2 = 0; a2 < 4; ++a2) {
    int row = r0 + ty * 4 + a2;
    const float* zp = Zs + (size_t)row * NCO + c0 + tx * 4;
    float* op = Os + (size_t)row * NCO + c0 + tx * 4;
    float4 z0 = *(const float4*)zp;
    float4 v0;
    v0.x = acc[a2][0] + z0.x; v0.y = acc[a2][1] + z0.y;
    v0.z = acc[a2][2] + z0.z; v0.w = acc[a2][3] + z0.w;
    z2 += z0.x * z0.x + z0.y * z0.y + z0.z * z0.z + z0.w * z0.w;
    *(float4*)op = v0;
  }
  __syncthreads();
  red[t] = z2;
  __syncthreads();
  for (int o = 128; o > 0; o >>= 1) {
    if (t < o) red[t] += red[t + o];
    __syncthreads();
  }
  if (t == 0) atomicAdd(&accum[s * 4 + 1], red[0]);
}

// ---- apply 2: sample = W^T * t1R (+ sum S^2)
__device__ void dev_app2(const float* Ws, const float* Rs, float* Op,
                         float* accum, int rb, int ch, int s, float* sm) {
  int r0 = rb * 64, c0 = ch * 64;
  float (*As_)[68] = (float(*)[68])sm;
  float (*Bs_)[68] = (float(*)[68])(sm + 1088);
  float* red = sm + 2176;
  int t = threadIdx.x, tx = t & 15, ty = t >> 4;
  float acc[4][4];
#pragma unroll
  for (int a = 0; a < 4; ++a)
#pragma unroll
    for (int b = 0; b < 4; ++b) acc[a][b] = 0.f;
  for (int k0 = r0; k0 < NFF; k0 += 16) {
    float4 a = *(const float4*)(Ws + (size_t)(k0 + (t >> 4)) * NFF + r0 + (t & 15) * 4);
    float4 bb = *(const float4*)(Rs + (size_t)(k0 + (t >> 4)) * NCO + c0 + (t & 15) * 4);
    __syncthreads();
    *(float4*)&As_[t >> 4][(t & 15) * 4] = a;
    *(float4*)&Bs_[t >> 4][(t & 15) * 4] = bb;
    __syncthreads();
#pragma unroll
    for (int kk = 0; kk < 16; ++kk) {
      float av[4], bv[4];
      *(float4*)&av[0] = *(const float4*)&As_[kk][ty * 4];
      *(float4*)&bv[0] = *(const float4*)&Bs_[kk][tx * 4];
#pragma unroll
      for (int a2 = 0; a2 < 4; ++a2)
#pragma unroll
        for (int b2 = 0; b2 < 4; ++b2) acc[a2][b2] = fmaf(av[a2], bv[b2], acc[a2][b2]);
    }
  }
  float s2 = 0.f;
#pragma unroll
  for (int b2 = 0; b2 < 4; ++b2) {
    int col = c0 + tx * 4 + b2;
    float4 v;
    v.x = acc[0][b2]; v.y = acc[1][b2]; v.z = acc[2][b2]; v.w = acc[3][b2];
    s2 += v.x * v.x + v.y * v.y + v.z * v.z + v.w * v.w;
    *(float4*)(Op + (size_t)col * NFF + r0 + ty * 4) = v;
  }
  __syncthreads();
  red[t] = s2;
  __syncthreads();
  for (int o = 128; o > 0; o >>= 1) {
    if (t < o) red[t] += red[t + o];
    __syncthreads();
  }
  if (t == 0) atomicAdd(&accum[s * 4 + 0], red[0]);
}

// ---- the fused persistent kernel: per-XCD sample pipelines, XCD-local sync
__global__ __launch_bounds__(256, 2) void k_coop(float* __restrict__ prec,
                                                 float* __restrict__ W,
                                                 const float* __restrict__ XLY,
                                                 float* __restrict__ t1R,
                                                 const float* __restrict__ Z,
                                                 float* __restrict__ out,
                                                 float* __restrict__ accum,
                                                 unsigned* __restrict__ syncmem) {
  __shared__ float SM[16896];   // 66 KB: max(panel 4*64*66, trail 2*64*68, inv1 4*64*65)
  __shared__ unsigned shr[2];
  int t = threadIdx.x;
  int wv = t >> 6, lane = t & 63;

  // ---- registration: physical XCD id -> group; role within group
  unsigned xcd;
  asm("s_getreg_b32 %0, hwreg(HW_REG_XCC_ID)" : "=s"(xcd));
  xcd &= 7u;
  unsigned* regcnt = syncmem;              // [0..8)
  unsigned* garr = syncmem + 8;            // [8]
  unsigned* go = syncmem + 64 + xcd * 16;  // padded per-XCD go word
  unsigned* slot = syncmem + 256 + xcd * 512;
  if (t == 0) {
    unsigned r = __hip_atomic_fetch_add(&regcnt[xcd], 1u,
                                        __ATOMIC_RELAXED, __HIP_MEMORY_SCOPE_AGENT);
    asm volatile("s_waitcnt vmcnt(0)" ::: "memory");   // regcnt RMW applied before arrive
    __hip_atomic_fetch_add(garr, 1u, __ATOMIC_RELAXED, __HIP_MEMORY_SCOPE_AGENT);
    while (__hip_atomic_load(garr, __ATOMIC_RELAXED, __HIP_MEMORY_SCOPE_AGENT) < gridDim.x)
      __builtin_amdgcn_s_sleep(8);
    shr[0] = r;
    shr[1] = __hip_atomic_load(&regcnt[xcd], __ATOMIC_RELAXED, __HIP_MEMORY_SCOPE_AGENT);
  }
  __syncthreads();
  unsigned role = shr[0], cnt = shr[1];

  int s = (int)xcd;                         // sample pinned to this XCD
  float* Ps = prec + (size_t)s * NFF * NFF;
  float* Wsb = W + (size_t)s * NFF * NFF;
  const float* Ys = XLY + (size_t)s * 147456;
  float* Rs = t1R + (size_t)s * 147456;
  const float* Zs = Z + (size_t)s * 147456;
  float* Outp = out + (size_t)s * 147456;
  unsigned ep = 0;
#define GS() xsync(slot, go, role, cnt, ++ep)

  // ---- phase 0: factor diag block 0 (1 wave task per sample)
  if (role == 0 && wv == 0) dev_fact64(Ps, &accum[s * 4 + 2], lane);
  GS();

  // ---- 17 cholesky steps: panels then trailing(+fused next diag)
  for (int p = 0; p < 17; ++p) {
    int m = 17 - p;
    for (unsigned tau = role * 4 + wv; tau < (unsigned)m; tau += cnt * 4)
      dev_panel(Ps, p, p + 1 + (int)tau, SM + wv * 4224);
    GS();
    unsigned nt = (unsigned)(m * (m + 1) / 2);
    for (unsigned tau = role; tau < nt; tau += cnt)
      dev_trail(Ps, &accum[s * 4 + 2], p, (int)tau, SM);
    GS();
  }

  // ---- inverse diag blocks (18 wave tasks per sample)
  for (unsigned tau = role * 4 + wv; tau < 18u; tau += cnt * 4) {
    const float* Pd = Ps + (size_t)(tau * 64) * NFF + tau * 64;
    float* Wd = Wsb + (size_t)(tau * 64) * NFF + tau * 64;
    dev_invdiag(Pd, Wd, lane);
  }
  GS();

  // ---- level-1 pair inverse (9 block tasks per sample)
  for (unsigned tau = role; tau < 9u; tau += cnt)
    dev_inv1(Ps, Wsb, (int)tau, SM);
  GS();

  // ---- recursive block-doubling levels: (n1, n2, nc, c0), npairs
  {
    const int LV[5][4] = { {2, 2, 2, 0}, {4, 4, 4, 0},
                           {8, 8, 4, 0}, {8, 8, 4, 4}, {16, 2, 16, 0} };
    const int NP[5] = {4, 2, 1, 1, 1};
    for (int lv = 0; lv < 5; ++lv) {
      int n1 = LV[lv][0], n2 = LV[lv][1], nc = LV[lv][2], c0 = LV[lv][3], np = NP[lv];
      unsigned ntask = (unsigned)(n2 * nc * np);
      for (unsigned tau = role; tau < ntask; tau += cnt) {
        unsigned q = tau;
        int r = (int)(q % (unsigned)n2); q /= (unsigned)n2;
        int ccb = (int)(q % (unsigned)nc); int pq = (int)(q / (unsigned)nc);
        dev_invA(Ps, Wsb, Rs, n1, n2, nc, c0, r, ccb, pq, SM);
      }
      GS();
      for (unsigned tau = role; tau < ntask; tau += cnt) {
        unsigned q = tau;
        int r = (int)(q % (unsigned)n2); q /= (unsigned)n2;
        int ccb = (int)(q % (unsigned)nc); int pq = (int)(q / (unsigned)nc);
        dev_invB(Wsb, Rs, n1, n2, nc, c0, r, ccb, pq, SM);
      }
      GS();
    }
  }

  // ---- apply 1 (36 block tasks per sample)
  for (unsigned tau = role; tau < 36u; tau += cnt) {
    int ch = (int)(tau & 1u), rb = (int)(tau >> 1);
    dev_app1(Wsb, Ys, Zs, Rs, accum, rb, ch, s, SM);
  }
  GS();
  // ---- apply 2 (36 block tasks per sample)
  for (unsigned tau = role; tau < 36u; tau += cnt) {
    int ch = (int)(tau & 1u), rb = (int)(tau >> 1);
    dev_app2(Wsb, Rs, Outp, accum, rb, ch, s, SM);
  }
  GS();
  // ---- final logpq (per-sample, by its XCD's role-0 block)
  if (role == 0 && t == 0) {
    float s2 = __hip_atomic_load(&accum[s * 4 + 0], __ATOMIC_RELAXED, __HIP_MEMORY_SCOPE_AGENT);
    float z2 = __hip_atomic_load(&accum[s * 4 + 1], __ATOMIC_RELAXED, __HIP_MEMORY_SCOPE_AGENT);
    float ld = __hip_atomic_load(&accum[s * 4 + 2], __ATOMIC_RELAXED, __HIP_MEMORY_SCOPE_AGENT);
    float logP = -0.5f * LAMV * s2 + 0.5f * (float)(NCO * NFF) * logf(LAMV);
    float logQ = -0.5f * z2 + 0.5f * (float)NCO * ld;
    out[(size_t)NS * 147456 + s] = logP - logQ;
  }
#undef GS
}

// ---------------------------------------------------------------- launch
extern "C" void kernel_launch(void* const* d_in, const int* in_sizes, int n_in,
                              void* d_out, int out_size, void* d_ws, size_t ws_size,
                              hipStream_t stream) {
  const float* X = (const float*)d_in[0];
  const float* u = (const float*)d_in[1];
  const float* lp = (const float*)d_in[2];
  const float* Z = (const float*)d_in[3];
  float* out = (float*)d_out;

  const size_t XU2 = 18874368;   // 1152*8192*2 (bf16), one s
  const size_t BM2 = 2097152;    // 128*8192*2
  const size_t FF4 = 5308416;    // 1152*1152*4
  const size_t FC4 = 589824;     // 1152*128*4
  const size_t FC = 147456;      // elems
  const size_t FF = 1327104;     // elems
  const size_t XSTR = 1048576;   // X elems per s

  int SB, kslices;
  if (ws_size >= ((size_t)206 << 20))      { SB = 8; kslices = 1; }
  else if (ws_size >= ((size_t)131 << 20)) { SB = 4; kslices = 2; }
  else                                     { SB = 2; kslices = 4; }

  char* ws = (char*)d_ws;
  size_t reg0 = (size_t)SB * XU2 + BM2;
  if (reg0 < 8 * FF4) reg0 = 8 * FF4;      // W aliases region0 after GEMMs
  unsigned short* Xu = (unsigned short*)ws;
  unsigned short* Bm = (unsigned short*)(ws + (size_t)SB * XU2);
  float* W = (float*)ws;
  size_t off = reg0;
  float* prec = (float*)(ws + off); off += 8 * FF4;
  float* XLY = (float*)(ws + off);  off += 8 * FC4;
  float* t1R = (float*)(ws + off);  off += 8 * FC4;   // also level-T scratch
  float* accum = (float*)(ws + off);
  unsigned* syncmem = (unsigned*)(ws + off + 512);    // regcnt/garr/go/slots

  k_build_B<<<4096, 256, 0, stream>>>(u, lp, Bm);
  hipMemsetAsync(accum, 0, 512 + 20480, stream);      // accum + sync region (per launch)
  if (kslices > 1) {
    hipMemsetAsync(prec, 0, 8 * FF4, stream);
    hipMemsetAsync(XLY, 0, 8 * FC4, stream);
    k_diag_init<<<dim3(5, 8), 256, 0, stream>>>(prec);
  }

  for (int pr = 0; pr < 8 / SB; ++pr) {
    k_build_Xu<<<36864, 256, 0, stream>>>(X + (size_t)pr * SB * XSTR, lp, Xu, SB);
    k_mfma<<<dim3(54, kslices, SB), 256, 0, stream>>>(Xu, Bm,
                                                      prec + (size_t)pr * SB * FF,
                                                      XLY + (size_t)pr * SB * FC,
                                                      8192 / kslices, kslices == 1 ? 1 : 0);
  }

  // fused: per-XCD sample pipelines (cholesky + inverse + apply + logpq)
  k_coop<<<COOPG, 256, 0, stream>>>(prec, W, XLY, t1R, Z, out, accum, syncmem);
}

// Round 8
// 1708.845 us; speedup vs baseline: 1.9726x; 1.0190x over previous
//
#include <hip/hip_runtime.h>
#include <hip/hip_bf16.h>
#include <math.h>

#define NS    8
#define NNI   32
#define NCI   128
#define NHH   16
#define NWW   16
#define NCO   128
#define NFF   1152
#define NLL   256
#define LAMV  1152.0f
#define COOPG 512

typedef short s8v __attribute__((ext_vector_type(8)));
typedef float f4v __attribute__((ext_vector_type(4)));

#define AS1 __attribute__((address_space(1)))
#define AS3 __attribute__((address_space(3)))

__device__ __forceinline__ float rdl(float v, int l) {
  return __uint_as_float(__builtin_amdgcn_readlane(__float_as_uint(v), (unsigned)l));
}

// ---------------------------------------------------------------- build Xu (bf16), z-loop inside
__global__ __launch_bounds__(256) void k_build_Xu(const float* __restrict__ X,
                                                  const float* __restrict__ lp,
                                                  unsigned short* __restrict__ Xu,
                                                  int nz) {
  unsigned idx = blockIdx.x * 256u + threadIdx.x;   // < 1152*8192
  unsigned m = idx & 8191u;
  unsigned f = idx >> 13;
  unsigned n = m >> 8, l = m & 255u, h = l >> 4, w = l & 15u;
  unsigned c = f / 9u, a = f - 9u * c;
  unsigned ki = a / 3u, kj = a - 3u * ki;
  int hi = (int)(h + ki) - 1, wi = (int)(w + kj) - 1;
  bool inb = (hi >= 0 && hi < NHH && wi >= 0 && wi < NWW);
  size_t xoff = (((size_t)n * NCI + c) << 8) + (size_t)(unsigned)(hi * NWW + wi);
  float spn = expf(0.5f * lp[n]);
  for (int z = 0; z < nz; ++z) {
    float v = inb ? X[(size_t)z * 1048576 + xoff] : 0.f;
    __hip_bfloat16 hv = __float2bfloat16(spn * v);
    Xu[(size_t)z * (NFF * 8192) + idx] = *(unsigned short*)&hv;
  }
}

__global__ __launch_bounds__(256) void k_build_B(const float* __restrict__ u,
                                                 const float* __restrict__ lp,
                                                 unsigned short* __restrict__ Bm) {
  unsigned idx = blockIdx.x * 256u + threadIdx.x;   // < 1,048,576
  unsigned m = idx & 8191u;
  unsigned c = idx >> 13;
  unsigned n = m >> 8, l = m & 255u;
  float spn = expf(0.5f * lp[n]);
  __hip_bfloat16 hv = __float2bfloat16(spn * u[((size_t)n * NCO + c) * NLL + l]);
  Bm[idx] = *(unsigned short*)&hv;
}

__global__ void k_diag_init(float* __restrict__ prec) {
  int s = blockIdx.y;
  int i = blockIdx.x * 256 + threadIdx.x;
  if (i < NFF) prec[(size_t)s * NFF * NFF + (size_t)i * NFF + i] = LAMV;
}

// ---------------------------------------------------------------- MFMA bf16 GEMM, SB s per launch
__global__ __launch_bounds__(256) void k_mfma(const unsigned short* __restrict__ XuBase,
                                              const unsigned short* __restrict__ Bm,
                                              float* __restrict__ prec,
                                              float* __restrict__ XLY,
                                              int kLen, int direct) {
  __shared__ unsigned short As[8192];
  __shared__ unsigned short Bs[8192];
  int z = blockIdx.z;
  const unsigned short* Xu = XuBase + (size_t)z * (NFF * 8192);
  prec += (size_t)z * NFF * NFF;
  XLY += (size_t)z * NFF * NCO;
  int bx = blockIdx.x;
  int row0, col0;
  const unsigned short* Ag;
  const unsigned short* Bg;
  bool isXLX;
  if (bx < 45) {
    int b = 0;
    while ((b + 1) * (b + 2) / 2 <= bx) b++;
    row0 = b * 128;
    col0 = (bx - b * (b + 1) / 2) * 128;
    Bg = Xu + (size_t)col0 * 8192;
    isXLX = true;
  } else {
    row0 = (bx - 45) * 128;
    col0 = 0;
    Bg = Bm;
    isXLX = false;
  }
  Ag = Xu + (size_t)row0 * 8192;

  int t = threadIdx.x;
  int lane = t & 63, w = t >> 6;
  int wm = w & 1, wn = w >> 1;
  int n16 = lane & 15, q = lane >> 4;
  int srow = lane >> 3, sch = lane & 7;

  f4v acc[4][4];
#pragma unroll
  for (int i = 0; i < 4; ++i)
#pragma unroll
    for (int j = 0; j < 4; ++j) acc[i][j] = (f4v)0.f;

  int kBase = blockIdx.y * kLen;
  for (int k0 = kBase; k0 < kBase + kLen; k0 += 64) {
    __syncthreads();
#pragma unroll
    for (int it = 0; it < 4; ++it) {
      int rA = (w * 4 + it) * 8 + srow;
      int cA = (sch - rA) & 7;
      const unsigned short* gpa = Ag + (size_t)rA * 8192 + k0 + cA * 8;
      const unsigned short* gpb = Bg + (size_t)rA * 8192 + k0 + cA * 8;
      __builtin_amdgcn_global_load_lds((AS1 const void*)gpa,
                                       (AS3 void*)&As[(w * 4 + it) * 512], 16, 0, 0);
      __builtin_amdgcn_global_load_lds((AS1 const void*)gpb,
                                       (AS3 void*)&Bs[(w * 4 + it) * 512], 16, 0, 0);
    }
    __syncthreads();
#pragma unroll
    for (int kk = 0; kk < 2; ++kk) {
      s8v af[4], bf[4];
#pragma unroll
      for (int im = 0; im < 4; ++im) {
        int r = wm * 64 + im * 16 + n16;
        int slot = ((kk * 4 + q) + r) & 7;
        af[im] = *(const s8v*)&As[r * 64 + slot * 8];
      }
#pragma unroll
      for (int in = 0; in < 4; ++in) {
        int r = wn * 64 + in * 16 + n16;
        int slot = ((kk * 4 + q) + r) & 7;
        bf[in] = *(const s8v*)&Bs[r * 64 + slot * 8];
      }
#pragma unroll
      for (int im = 0; im < 4; ++im)
#pragma unroll
        for (int in = 0; in < 4; ++in)
          acc[im][in] = __builtin_amdgcn_mfma_f32_16x16x32_bf16(af[im], bf[in], acc[im][in], 0, 0, 0);
    }
  }

#pragma unroll
  for (int im = 0; im < 4; ++im)
#pragma unroll
    for (int in = 0; in < 4; ++in) {
      int gr = row0 + wm * 64 + im * 16 + q * 4;
      int gc = (isXLX ? col0 : 0) + wn * 64 + in * 16 + n16;
      if (direct) {
        if (isXLX) {
#pragma unroll
          for (int tt = 0; tt < 4; ++tt)
            prec[(size_t)(gr + tt) * NFF + gc] =
                acc[im][in][tt] + ((gr + tt) == gc ? LAMV : 0.f);
        } else {
#pragma unroll
          for (int tt = 0; tt < 4; ++tt)
            XLY[(size_t)(gr + tt) * NCO + gc] = acc[im][in][tt];
        }
      } else {
        if (isXLX) {
#pragma unroll
          for (int tt = 0; tt < 4; ++tt)
            atomicAdd(&prec[(size_t)(gr + tt) * NFF + gc], acc[im][in][tt]);
        } else {
#pragma unroll
          for (int tt = 0; tt < 4; ++tt)
            atomicAdd(&XLY[(size_t)(gr + tt) * NCO + gc], acc[im][in][tt]);
        }
      }
    }
}

// ================================================================ persistent fused kernel
// XCD-local barrier (validated rounds 6-7). Round-8 variable: the Cholesky trailing
// triangle lives in LDS (persistent tile ownership: tile t=i(i+1)/2+j, owner=t%cnt,
// slot=t/cnt, [64][68]-padded). Panels/diag are broadcast through global (L2-hot);
// trailing RMW never touches global.
__device__ __forceinline__ void xsync(unsigned* slot, unsigned* go, unsigned role,
                                      unsigned cnt, unsigned ep) {
  __syncthreads();   // drains vmcnt: all block stores are in the XCD's L2
  int t = threadIdx.x;
  if (t == 0)
    __hip_atomic_store(&slot[role], ep, __ATOMIC_RELAXED, __HIP_MEMORY_SCOPE_AGENT);
  if (role == 0) {
    if (t < 64) {
      for (;;) {
        unsigned ok = 1;
        for (unsigned i = (unsigned)t; i < cnt; i += 64u)
          ok &= (__hip_atomic_load(&slot[i], __ATOMIC_RELAXED, __HIP_MEMORY_SCOPE_AGENT) >= ep)
                    ? 1u : 0u;
        if (__all((int)ok)) break;
        __builtin_amdgcn_s_sleep(2);
      }
      if (t == 0)
        __hip_atomic_store(go, ep, __ATOMIC_RELAXED, __HIP_MEMORY_SCOPE_AGENT);
    }
  } else if (t == 0) {
    while (__hip_atomic_load(go, __ATOMIC_RELAXED, __HIP_MEMORY_SCOPE_AGENT) < ep)
      __builtin_amdgcn_s_sleep(2);
  }
  __syncthreads();
  asm volatile("buffer_inv" ::: "memory");   // vL1 invalidate (CU-local, cheap)
  __syncthreads();
}

// ---- factor 64x64 diag block from GLOBAL (fallback path, one wave)
__device__ void dev_fact64(float* D, float* accum_ld, int lane) {
  float x[64];
#pragma unroll
  for (int k = 0; k < 64; ++k) x[k] = D[(size_t)lane * NFF + k];
  float ld = 0.f;
#pragma unroll
  for (int k = 0; k < 64; ++k) {
    float dk = sqrtf(rdl(x[k], k));
    float inv = 1.0f / dk;
    ld += logf(dk);
    x[k] = (lane == k) ? dk : ((lane > k) ? x[k] * inv : x[k]);
#pragma unroll
    for (int kk = k + 1; kk < 64; ++kk)
      x[kk] = fmaf(-x[k], rdl(x[k], kk), x[kk]);
  }
  if (lane == 0) atomicAdd(accum_ld, 2.f * ld);
#pragma unroll
  for (int k = 0; k < 64; ++k) D[(size_t)lane * NFF + k] = x[k];
}

// ---- factor 64x64 diag block from LDS tile [64][68]; write result to global diag row
__device__ void dev_factLds(const float* T68, float* Dg, float* accum_ld, int lane) {
  float x[64];
#pragma unroll
  for (int k = 0; k < 64; ++k) x[k] = T68[lane * 68 + k];
  float ld = 0.f;
#pragma unroll
  for (int k = 0; k < 64; ++k) {
    float dk = sqrtf(rdl(x[k], k));
    float inv = 1.0f / dk;
    ld += logf(dk);
    x[k] = (lane == k) ? dk : ((lane > k) ? x[k] * inv : x[k]);
#pragma unroll
    for (int kk = k + 1; kk < 64; ++kk)
      x[kk] = fmaf(-x[k], rdl(x[k], kk), x[kk]);
  }
  if (lane == 0) atomicAdd(accum_ld, 2.f * ld);
#pragma unroll
  for (int k = 0; k < 64; ++k) Dg[(size_t)lane * NFF + k] = x[k];
}

// ---- panel solve X * L_pp^T = A(i,p) from LDS tile; write transposed-upper (p,i).
// Note: At[r][lane] = X[lane][r] is each lane's OWN x[r] -> no cross-lane transpose needed.
__device__ void dev_panelLds(const float* T68, const float* Dg, float* At, int lane) {
  float Lc[64];
#pragma unroll
  for (int k = 0; k < 64; ++k) Lc[k] = Dg[(size_t)k * NFF + lane];
  float x[64];
#pragma unroll
  for (int k = 0; k < 64; ++k) x[k] = T68[lane * 68 + k];
#pragma unroll
  for (int j = 0; j < 64; ++j) {
    float xj = x[j] / rdl(Lc[j], j);
    x[j] = xj;
#pragma unroll
    for (int k = j + 1; k < 64; ++k)
      x[k] = fmaf(-xj, rdl(Lc[k], j), x[k]);
  }
#pragma unroll
  for (int r = 0; r < 64; ++r) At[(size_t)r * NFF + lane] = x[r];
}

// ---- panel solve from GLOBAL tile (fallback for non-LDS-resident tiles)
__device__ void dev_panelGlb(const float* AiG, const float* Dg, float* At, int lane) {
  float Lc[64];
#pragma unroll
  for (int k = 0; k < 64; ++k) Lc[k] = Dg[(size_t)k * NFF + lane];
  float x[64];
#pragma unroll
  for (int k = 0; k < 64; ++k) x[k] = AiG[(size_t)lane * NFF + k];
#pragma unroll
  for (int j = 0; j < 64; ++j) {
    float xj = x[j] / rdl(Lc[j], j);
    x[j] = xj;
#pragma unroll
    for (int k = j + 1; k < 64; ++k)
      x[k] = fmaf(-xj, rdl(Lc[k], j), x[k]);
  }
#pragma unroll
  for (int r = 0; r < 64; ++r) At[(size_t)r * NFF + lane] = x[r];
}

// ---- trailing update C(i,j) -= P_i P_j^T. Panels staged from L2 in 16-row chunks
// (8.7KB scratch); destination is the owner's LDS tile (or global for fallback tiles).
// K-accumulation order identical to the verified full-tile version.
__device__ void dev_trail2(float* Ps, float* tileT, int p, int i, int j, float* csm) {
  const float* Ui = Ps + (size_t)(p * 64) * NFF + i * 64;
  const float* Uj = Ps + (size_t)(p * 64) * NFF + j * 64;
  float (*Ak)[68] = (float(*)[68])csm;
  float (*Bk)[68] = (float(*)[68])(csm + 1088);
  int t = threadIdx.x, tx = t & 15, ty = t >> 4;
  float acc[4][4];
#pragma unroll
  for (int a = 0; a < 4; ++a)
#pragma unroll
    for (int b2 = 0; b2 < 4; ++b2) acc[a][b2] = 0.f;
  for (int k0 = 0; k0 < 64; k0 += 16) {
    float4 a = *(const float4*)(Ui + (size_t)(k0 + ty) * NFF + tx * 4);
    float4 b = *(const float4*)(Uj + (size_t)(k0 + ty) * NFF + tx * 4);
    __syncthreads();
    *(float4*)&Ak[ty][tx * 4] = a;
    *(float4*)&Bk[ty][tx * 4] = b;
    __syncthreads();
#pragma unroll
    for (int kk = 0; kk < 16; ++kk) {
      float av[4], bv[4];
      *(float4*)&av[0] = *(const float4*)&Ak[kk][ty * 4];
      *(float4*)&bv[0] = *(const float4*)&Bk[kk][tx * 4];
#pragma unroll
      for (int a2 = 0; a2 < 4; ++a2)
#pragma unroll
        for (int b2 = 0; b2 < 4; ++b2) acc[a2][b2] = fmaf(av[a2], bv[b2], acc[a2][b2]);
    }
  }
  if (tileT) {
#pragma unroll
    for (int a = 0; a < 4; ++a) {
      float4* cp = (float4*)&tileT[(ty * 4 + a) * 68 + tx * 4];
      float4 cv = *cp;
      cv.x -= acc[a][0]; cv.y -= acc[a][1]; cv.z -= acc[a][2]; cv.w -= acc[a][3];
      *cp = cv;
    }
  } else {
    float* Cb = Ps + (size_t)(i * 64) * NFF + j * 64;
#pragma unroll
    for (int a = 0; a < 4; ++a) {
      float4* cp = (float4*)(Cb + (size_t)(ty * 4 + a) * NFF + tx * 4);
      float4 cv = *cp;
      cv.x -= acc[a][0]; cv.y -= acc[a][1]; cv.z -= acc[a][2]; cv.w -= acc[a][3];
      *cp = cv;
    }
  }
}

// ---- inverse of diag block (one wave): lane j holds column j of Linv
__device__ void dev_invdiag(const float* Ps, float* Ws, int lane) {
  float Lr[64];
#pragma unroll
  for (int m = 0; m < 64; ++m) Lr[m] = Ps[(size_t)lane * NFF + m];
  float x[64];
#pragma unroll
  for (int k = 0; k < 64; ++k) {
    float v = (lane == k) ? 1.f : 0.f;
#pragma unroll
    for (int m = 0; m < k; ++m)
      v = fmaf(-rdl(Lr[m], k), x[m], v);
    x[k] = v / rdl(Lr[k], k);
  }
#pragma unroll
  for (int k = 0; k < 64; ++k) Ws[(size_t)k * NFF + lane] = x[k];
}

// ---- level-1 pair inverse: W[2p+1][2p] = -D2 * L21 * D1
__device__ void dev_inv1(const float* Ps, float* Ws, int p, float* sm) {
  int J = 2 * p, I = 2 * p + 1;
  float (*Ak)[65] = (float(*)[65])sm;
  float (*Bk)[65] = (float(*)[65])(sm + 4160);
  float (*Dk)[65] = (float(*)[65])(sm + 8320);
  float (*Tt)[65] = (float(*)[65])(sm + 12480);
  int t = threadIdx.x, tx = t & 15, ty = t >> 4;
  __syncthreads();
  for (int e = t; e < 4096; e += 256) {
    int r = e >> 6, cc = e & 63;
    Ak[r][cc] = Ps[(size_t)(J * 64 + r) * NFF + I * 64 + cc];
    Bk[r][cc] = Ws[(size_t)(J * 64 + r) * NFF + J * 64 + cc];
  }
  {
    int i = t >> 2;
#pragma unroll
    for (int it = 0; it < 4; ++it) {
      int kq = (t & 3) * 4 + it * 16;
      float4 a = *(const float4*)&Ws[(size_t)(I * 64 + i) * NFF + I * 64 + kq];
      Dk[kq + 0][i] = a.x; Dk[kq + 1][i] = a.y; Dk[kq + 2][i] = a.z; Dk[kq + 3][i] = a.w;
    }
  }
  __syncthreads();
  float acc[4][4];
#pragma unroll
  for (int a = 0; a < 4; ++a)
#pragma unroll
    for (int b = 0; b < 4; ++b) acc[a][b] = 0.f;
#pragma unroll 8
  for (int kk = 0; kk < 64; ++kk) {
    float av[4], bv[4];
#pragma unroll
    for (int a = 0; a < 4; ++a) av[a] = Ak[kk][ty * 4 + a];
#pragma unroll
    for (int b = 0; b < 4; ++b) bv[b] = Bk[kk][tx * 4 + b];
#pragma unroll
    for (int a = 0; a < 4; ++a)
#pragma unroll
      for (int b = 0; b < 4; ++b) acc[a][b] = fmaf(av[a], bv[b], acc[a][b]);
  }
#pragma unroll
  for (int a = 0; a < 4; ++a)
#pragma unroll
    for (int b = 0; b < 4; ++b) Tt[ty * 4 + a][tx * 4 + b] = acc[a][b];
  __syncthreads();
  float a2[4][4];
#pragma unroll
  for (int a = 0; a < 4; ++a)
#pragma unroll
    for (int b = 0; b < 4; ++b) a2[a][b] = 0.f;
#pragma unroll 8
  for (int kk = 0; kk < 64; ++kk) {
    float av[4], bv[4];
#pragma unroll
    for (int a = 0; a < 4; ++a) av[a] = Dk[kk][ty * 4 + a];
#pragma unroll
    for (int b = 0; b < 4; ++b) bv[b] = Tt[kk][tx * 4 + b];
#pragma unroll
    for (int a = 0; a < 4; ++a)
#pragma unroll
      for (int b = 0; b < 4; ++b) a2[a][b] = fmaf(av[a], bv[b], a2[a][b]);
  }
#pragma unroll
  for (int a = 0; a < 4; ++a) {
    float4 o;
    o.x = -a2[a][0]; o.y = -a2[a][1]; o.z = -a2[a][2]; o.w = -a2[a][3];
    *(float4*)&Ws[(size_t)(I * 64 + ty * 4 + a) * NFF + J * 64 + tx * 4] = o;
  }
}

// ---- level kernel A: T = L21 * W11 (tile r, col-block c)
__device__ void dev_invA(const float* Ps, const float* Ws, float* Tbs,
                         int n1, int n2, int nc, int c0, int r, int ccb, int pq,
                         float* sm) {
  int ldT = nc * 64;
  int o = pq * 2 * n1;
  int I = o + n1 + r, c = c0 + ccb;
  float* Ts = Tbs + (size_t)pq * (size_t)(n2 * 64) * ldT;
  float (*Aks)[68] = (float(*)[68])sm;
  float (*Bks)[68] = (float(*)[68])(sm + 1088);
  int t = threadIdx.x, tx = t & 15, ty = t >> 4;
  float acc[4][4];
#pragma unroll
  for (int a = 0; a < 4; ++a)
#pragma unroll
    for (int b = 0; b < 4; ++b) acc[a][b] = 0.f;
  for (int kb = c; kb < n1; ++kb) {
    const float* up = Ps + (size_t)((o + kb) * 64) * NFF + I * 64;
    const float* wp = Ws + (size_t)((o + kb) * 64) * NFF + (o + c) * 64;
    for (int k0 = 0; k0 < 64; k0 += 16) {
      float4 a = *(const float4*)(up + (size_t)(k0 + ty) * NFF + tx * 4);
      float4 b = *(const float4*)(wp + (size_t)(k0 + ty) * NFF + tx * 4);
      __syncthreads();
      *(float4*)&Aks[ty][tx * 4] = a;
      *(float4*)&Bks[ty][tx * 4] = b;
      __syncthreads();
#pragma unroll
      for (int kk = 0; kk < 16; ++kk) {
        float av[4], bv[4];
        *(float4*)&av[0] = *(const float4*)&Aks[kk][ty * 4];
        *(float4*)&bv[0] = *(const float4*)&Bks[kk][tx * 4];
#pragma unroll
        for (int a2 = 0; a2 < 4; ++a2)
#pragma unroll
          for (int b2 = 0; b2 < 4; ++b2) acc[a2][b2] = fmaf(av[a2], bv[b2], acc[a2][b2]);
      }
    }
  }
#pragma unroll
  for (int a = 0; a < 4; ++a) {
    float4 v;
    v.x = acc[a][0]; v.y = acc[a][1]; v.z = acc[a][2]; v.w = acc[a][3];
    *(float4*)(Ts + (size_t)(r * 64 + ty * 4 + a) * ldT + ccb * 64 + tx * 4) = v;
  }
}

// ---- level kernel B: W21 = -W22 * T
__device__ void dev_invB(float* Ws, const float* Tbs,
                         int n1, int n2, int nc, int c0, int r, int ccb, int pq,
                         float* sm) {
  int ldT = nc * 64;
  int o = pq * 2 * n1;
  int I = o + n1 + r, c = c0 + ccb;
  const float* Ts = Tbs + (size_t)pq * (size_t)(n2 * 64) * ldT;
  float (*Aks)[68] = (float(*)[68])sm;
  float (*Bks)[68] = (float(*)[68])(sm + 1088);
  int t = threadIdx.x, tx = t & 15, ty = t >> 4;
  float acc[4][4];
#pragma unroll
  for (int a = 0; a < 4; ++a)
#pragma unroll
    for (int b = 0; b < 4; ++b) acc[a][b] = 0.f;
  for (int kb = 0; kb <= r; ++kb) {
    const float* ap = Ws + (size_t)(I * 64) * NFF + (o + n1 + kb) * 64;
    const float* tp = Ts + (size_t)(kb * 64) * ldT + ccb * 64;
    for (int k0 = 0; k0 < 64; k0 += 16) {
      float4 a = *(const float4*)(ap + (size_t)(t >> 2) * NFF + k0 + (t & 3) * 4);
      float4 b = *(const float4*)(tp + (size_t)(k0 + ty) * ldT + tx * 4);
      __syncthreads();
      Aks[(t & 3) * 4 + 0][t >> 2] = a.x;
      Aks[(t & 3) * 4 + 1][t >> 2] = a.y;
      Aks[(t & 3) * 4 + 2][t >> 2] = a.z;
      Aks[(t & 3) * 4 + 3][t >> 2] = a.w;
      *(float4*)&Bks[ty][tx * 4] = b;
      __syncthreads();
#pragma unroll
      for (int kk = 0; kk < 16; ++kk) {
        float av[4], bv[4];
        *(float4*)&av[0] = *(const float4*)&Aks[kk][ty * 4];
        *(float4*)&bv[0] = *(const float4*)&Bks[kk][tx * 4];
#pragma unroll
        for (int a2 = 0; a2 < 4; ++a2)
#pragma unroll
          for (int b2 = 0; b2 < 4; ++b2) acc[a2][b2] = fmaf(av[a2], bv[b2], acc[a2][b2]);
      }
    }
  }
#pragma unroll
  for (int a = 0; a < 4; ++a) {
    float4 v;
    v.x = -acc[a][0]; v.y = -acc[a][1]; v.z = -acc[a][2]; v.w = -acc[a][3];
    *(float4*)&Ws[(size_t)(I * 64 + ty * 4 + a) * NFF + (o + c) * 64 + tx * 4] = v;
  }
}

// ---- apply 1: t1R = W*XLY + Z (+ sum Z^2)
__device__ void dev_app1(const float* Ws, const float* Ys, const float* Zs,
                         float* Os, float* accum, int rb, int ch, int s, float* sm) {
  int r0 = rb * 64, c0 = ch * 64;
  float (*As_)[68] = (float(*)[68])sm;
  float (*Bs_)[68] = (float(*)[68])(sm + 1088);
  float* red = sm + 2176;
  int t = threadIdx.x, tx = t & 15, ty = t >> 4;
  float acc[4][4];
#pragma unroll
  for (int a = 0; a < 4; ++a)
#pragma unroll
    for (int b = 0; b < 4; ++b) acc[a][b] = 0.f;
  int kmax = r0 + 64;
  for (int k0 = 0; k0 < kmax; k0 += 16) {
    float4 a = *(const float4*)(Ws + (size_t)(r0 + (t >> 2)) * NFF + k0 + (t & 3) * 4);
    float4 bb = *(const float4*)(Ys + (size_t)(k0 + (t >> 4)) * NCO + c0 + (t & 15) * 4);
    __syncthreads();
    As_[(t & 3) * 4 + 0][t >> 2] = a.x; As_[(t & 3) * 4 + 1][t >> 2] = a.y;
    As_[(t & 3) * 4 + 2][t >> 2] = a.z; As_[(t & 3) * 4 + 3][t >> 2] = a.w;
    *(float4*)&Bs_[t >> 4][(t & 15) * 4] = bb;
    __syncthreads();
#pragma unroll
    for (int kk = 0; kk < 16; ++kk) {
      float av[4], bv[4];
      *(float4*)&av[0] = *(const float4*)&As_[kk][ty * 4];
      *(float4*)&bv[0] = *(const float4*)&Bs_[kk][tx * 4];
#pragma unroll
      for (int a2 = 0; a2 < 4; ++a2)
#pragma unroll
        for (int b2 = 0; b2 < 4; ++b2) acc[a2][b2] = fmaf(av[a2], bv[b2], acc[a2][b2]);
    }
  }
  float z2 = 0.f;
#pragma unroll
  for (int a2 = 0; a2 < 4; ++a2) {
    int row = r0 + ty * 4 + a2;
    const float* zp = Zs + (size_t)row * NCO + c0 + tx * 4;
    float* op = Os + (size_t)row * NCO + c0 + tx * 4;
    float4 z0 = *(const float4*)zp;
    float4 v0;
    v0.x = acc[a2][0] + z0.x; v0.y = acc[a2][1] + z0.y;
    v0.z = acc[a2][2] + z0.z; v0.w = acc[a2][3] + z0.w;
    z2 += z0.x * z0.x + z0.y * z0.y + z0.z * z0.z + z0.w * z0.w;
    *(float4*)op = v0;
  }
  __syncthreads();
  red[t] = z2;
  __syncthreads();
  for (int o = 128; o > 0; o >>= 1) {
    if (t < o) red[t] += red[t + o];
    __syncthreads();
  }
  if (t == 0) atomicAdd(&accum[s * 4 + 1], red[0]);
}

// ---- apply 2: sample = W^T * t1R (+ sum S^2)
__device__ void dev_app2(const float* Ws, const float* Rs, float* Op,
                         float* accum, int rb, int ch, int s, float* sm) {
  int r0 = rb * 64, c0 = ch * 64;
  float (*As_)[68] = (float(*)[68])sm;
  float (*Bs_)[68] = (float(*)[68])(sm + 1088);
  float* red = sm + 2176;
  int t = threadIdx.x, tx = t & 15, ty = t >> 4;
  float acc[4][4];
#pragma unroll
  for (int a = 0; a < 4; ++a)
#pragma unroll
    for (int b = 0; b < 4; ++b) acc[a][b] = 0.f;
  for (int k0 = r0; k0 < NFF; k0 += 16) {
    float4 a = *(const float4*)(Ws + (size_t)(k0 + (t >> 4)) * NFF + r0 + (t & 15) * 4);
    float4 bb = *(const float4*)(Rs + (size_t)(k0 + (t >> 4)) * NCO + c0 + (t & 15) * 4);
    __syncthreads();
    *(float4*)&As_[t >> 4][(t & 15) * 4] = a;
    *(float4*)&Bs_[t >> 4][(t & 15) * 4] = bb;
    __syncthreads();
#pragma unroll
    for (int kk = 0; kk < 16; ++kk) {
      float av[4], bv[4];
      *(float4*)&av[0] = *(const float4*)&As_[kk][ty * 4];
      *(float4*)&bv[0] = *(const float4*)&Bs_[kk][tx * 4];
#pragma unroll
      for (int a2 = 0; a2 < 4; ++a2)
#pragma unroll
        for (int b2 = 0; b2 < 4; ++b2) acc[a2][b2] = fmaf(av[a2], bv[b2], acc[a2][b2]);
    }
  }
  float s2 = 0.f;
#pragma unroll
  for (int b2 = 0; b2 < 4; ++b2) {
    int col = c0 + tx * 4 + b2;
    float4 v;
    v.x = acc[0][b2]; v.y = acc[1][b2]; v.z = acc[2][b2]; v.w = acc[3][b2];
    s2 += v.x * v.x + v.y * v.y + v.z * v.z + v.w * v.w;
    *(float4*)(Op + (size_t)col * NFF + r0 + ty * 4) = v;
  }
  __syncthreads();
  red[t] = s2;
  __syncthreads();
  for (int o = 128; o > 0; o >>= 1) {
    if (t < o) red[t] += red[t + o];
    __syncthreads();
  }
  if (t == 0) atomicAdd(&accum[s * 4 + 0], red[0]);
}

// ---- the fused persistent kernel: per-XCD sample pipelines, LDS-resident Cholesky
__global__ __launch_bounds__(256, 2) void k_coop(float* __restrict__ prec,
                                                 float* __restrict__ W,
                                                 const float* __restrict__ XLY,
                                                 float* __restrict__ t1R,
                                                 const float* __restrict__ Z,
                                                 float* __restrict__ out,
                                                 float* __restrict__ accum,
                                                 unsigned* __restrict__ syncmem) {
  // 66KB LDS: chol = 3 tiles [64][68] @ 0/4352/8704 + 2x[16][68] chunk scratch @ 13056.
  // inverse phases reuse SM base (inv1 needs 16640 floats).
  __shared__ float SM[16896];
  __shared__ unsigned shr[2];
  int t = threadIdx.x;
  int wv = t >> 6, lane = t & 63;

  // ---- registration: physical XCD id -> group; role within group
  unsigned xcd;
  asm("s_getreg_b32 %0, hwreg(HW_REG_XCC_ID)" : "=s"(xcd));
  xcd &= 7u;
  unsigned* regcnt = syncmem;              // [0..8)
  unsigned* garr = syncmem + 8;            // [8]
  unsigned* go = syncmem + 64 + xcd * 16;  // padded per-XCD go word
  unsigned* slot = syncmem + 256 + xcd * 512;
  if (t == 0) {
    unsigned r = __hip_atomic_fetch_add(&regcnt[xcd], 1u,
                                        __ATOMIC_RELAXED, __HIP_MEMORY_SCOPE_AGENT);
    asm volatile("s_waitcnt vmcnt(0)" ::: "memory");   // regcnt RMW applied before arrive
    __hip_atomic_fetch_add(garr, 1u, __ATOMIC_RELAXED, __HIP_MEMORY_SCOPE_AGENT);
    while (__hip_atomic_load(garr, __ATOMIC_RELAXED, __HIP_MEMORY_SCOPE_AGENT) < gridDim.x)
      __builtin_amdgcn_s_sleep(8);
    shr[0] = r;
    shr[1] = __hip_atomic_load(&regcnt[xcd], __ATOMIC_RELAXED, __HIP_MEMORY_SCOPE_AGENT);
  }
  __syncthreads();
  unsigned role = shr[0], cnt = shr[1];

  int smp = (int)xcd;                       // sample pinned to this XCD
  float* Ps = prec + (size_t)smp * NFF * NFF;
  float* Wsb = W + (size_t)smp * NFF * NFF;
  const float* Ys = XLY + (size_t)smp * 147456;
  float* Rs = t1R + (size_t)smp * 147456;
  const float* Zs = Z + (size_t)smp * 147456;
  float* Outp = out + (size_t)smp * 147456;
  unsigned ep = 0;
#define GS() xsync(slot, go, role, cnt, ++ep)

  // ---- tile ownership: tile tt = i(i+1)/2+j (171 tiles), owner = tt % cnt, slot = tt / cnt
  int ti[3], tj[3];
  bool tv[3];
#pragma unroll
  for (int sl = 0; sl < 3; ++sl) {
    unsigned tt = role + (unsigned)sl * cnt;
    tv[sl] = (tt < 171u);
    ti[sl] = 0; tj[sl] = 0;
    if (tv[sl]) {
      int i = 0;
      while ((unsigned)((i + 1) * (i + 2) / 2) <= tt) ++i;
      ti[sl] = i;
      tj[sl] = (int)tt - i * (i + 1) / 2;
    }
  }

  // ---- load owned tiles global -> LDS
#pragma unroll
  for (int sl = 0; sl < 3; ++sl)
    if (tv[sl]) {
      const float* Gb = Ps + (size_t)(ti[sl] * 64) * NFF + tj[sl] * 64;
      float* T = SM + sl * 4352;
      for (int e = t; e < 1024; e += 256) {
        int r = e >> 4, c4 = (e & 15) * 4;
        *(float4*)&T[r * 68 + c4] = *(const float4*)(Gb + (size_t)r * NFF + c4);
      }
    }
  __syncthreads();

  // ---- phase 0: factor diag (0,0) — tile 0 is owned by role 0, slot 0
  if (role == 0 && t < 64) dev_factLds(SM, Ps, &accum[smp * 4 + 2], t);
  GS();

  // ---- 17 cholesky steps: panel solves (from LDS), trailing LDS-RMW (+fused next diag)
  for (int p = 0; p < 17; ++p) {
    // panels: wave sl handles slot sl (no block-level sync inside)
#pragma unroll
    for (int sl = 0; sl < 3; ++sl)
      if (wv == sl && tv[sl] && tj[sl] == p && ti[sl] > p)
        dev_panelLds(SM + sl * 4352, Ps + (size_t)(p * 64) * NFF + p * 64,
                     Ps + (size_t)(p * 64) * NFF + ti[sl] * 64, lane);
    if (cnt < 57u && wv == 3) {
      for (unsigned tt = role + 3u * cnt; tt < 171u; tt += cnt) {
        int i = 0;
        while ((unsigned)((i + 1) * (i + 2) / 2) <= tt) ++i;
        int j = (int)tt - i * (i + 1) / 2;
        if (j == p && i > p)
          dev_panelGlb(Ps + (size_t)(i * 64) * NFF + p * 64,
                       Ps + (size_t)(p * 64) * NFF + p * 64,
                       Ps + (size_t)(p * 64) * NFF + i * 64, lane);
      }
    }
    GS();
    // trailing updates (block-uniform guards; dev_trail2 has internal syncthreads)
#pragma unroll
    for (int sl = 0; sl < 3; ++sl)
      if (tv[sl] && ti[sl] > p && tj[sl] > p)
        dev_trail2(Ps, SM + sl * 4352, p, ti[sl], tj[sl], SM + 13056);
    if (cnt < 57u) {
      for (unsigned tt = role + 3u * cnt; tt < 171u; tt += cnt) {
        int i = 0;
        while ((unsigned)((i + 1) * (i + 2) / 2) <= tt) ++i;
        int j = (int)tt - i * (i + 1) / 2;
        if (i > p && j > p) dev_trail2(Ps, nullptr, p, i, j, SM + 13056);
      }
    }
    // fused factor of next diag (p+1,p+1)
    {
      int dn = p + 1;
#pragma unroll
      for (int sl = 0; sl < 3; ++sl)
        if (tv[sl] && ti[sl] == dn && tj[sl] == dn) {
          __syncthreads();   // tile updated by all 256 threads; wave 0 reads it all
          if (t < 64)
            dev_factLds(SM + sl * 4352, Ps + (size_t)(dn * 64) * NFF + dn * 64,
                        &accum[smp * 4 + 2], t);
        }
      if (cnt < 57u) {
        unsigned td = (unsigned)(dn * (dn + 1) / 2 + dn);
        if (td % cnt == role && td / cnt >= 3u) {
          __syncthreads();
          asm volatile("buffer_inv" ::: "memory");   // re-read own RMW'd lines from L2
          if (t < 64)
            dev_fact64(Ps + (size_t)(dn * 64) * NFF + dn * 64, &accum[smp * 4 + 2], t);
        }
      }
    }
    GS();
  }

  // ---- inverse diag blocks (18 wave tasks per sample)
  for (unsigned tau = role * 4 + wv; tau < 18u; tau += cnt * 4) {
    const float* Pd = Ps + (size_t)(tau * 64) * NFF + tau * 64;
    float* Wd = Wsb + (size_t)(tau * 64) * NFF + tau * 64;
    dev_invdiag(Pd, Wd, lane);
  }
  GS();

  // ---- level-1 pair inverse (9 block tasks per sample)
  for (unsigned tau = role; tau < 9u; tau += cnt)
    dev_inv1(Ps, Wsb, (int)tau, SM);
  GS();

  // ---- recursive block-doubling levels: (n1, n2, nc, c0), npairs
  {
    const int LV[5][4] = { {2, 2, 2, 0}, {4, 4, 4, 0},
                           {8, 8, 4, 0}, {8, 8, 4, 4}, {16, 2, 16, 0} };
    const int NP[5] = {4, 2, 1, 1, 1};
    for (int lv = 0; lv < 5; ++lv) {
      int n1 = LV[lv][0], n2 = LV[lv][1], nc = LV[lv][2], c0 = LV[lv][3], np = NP[lv];
      unsigned ntask = (unsigned)(n2 * nc * np);
      for (unsigned tau = role; tau < ntask; tau += cnt) {
        unsigned q = tau;
        int r = (int)(q % (unsigned)n2); q /= (unsigned)n2;
        int ccb = (int)(q % (unsigned)nc); int pq = (int)(q / (unsigned)nc);
        dev_invA(Ps, Wsb, Rs, n1, n2, nc, c0, r, ccb, pq, SM);
      }
      GS();
      for (unsigned tau = role; tau < ntask; tau += cnt) {
        unsigned q = tau;
        int r = (int)(q % (unsigned)n2); q /= (unsigned)n2;
        int ccb = (int)(q % (unsigned)nc); int pq = (int)(q / (unsigned)nc);
        dev_invB(Wsb, Rs, n1, n2, nc, c0, r, ccb, pq, SM);
      }
      GS();
    }
  }

  // ---- apply 1 (36 block tasks per sample)
  for (unsigned tau = role; tau < 36u; tau += cnt) {
    int ch = (int)(tau & 1u), rb = (int)(tau >> 1);
    dev_app1(Wsb, Ys, Zs, Rs, accum, rb, ch, smp, SM);
  }
  GS();
  // ---- apply 2 (36 block tasks per sample)
  for (unsigned tau = role; tau < 36u; tau += cnt) {
    int ch = (int)(tau & 1u), rb = (int)(tau >> 1);
    dev_app2(Wsb, Rs, Outp, accum, rb, ch, smp, SM);
  }
  GS();
  // ---- final logpq (per-sample, by its XCD's role-0 block)
  if (role == 0 && t == 0) {
    float s2 = __hip_atomic_load(&accum[smp * 4 + 0], __ATOMIC_RELAXED, __HIP_MEMORY_SCOPE_AGENT);
    float z2 = __hip_atomic_load(&accum[smp * 4 + 1], __ATOMIC_RELAXED, __HIP_MEMORY_SCOPE_AGENT);
    float ld = __hip_atomic_load(&accum[smp * 4 + 2], __ATOMIC_RELAXED, __HIP_MEMORY_SCOPE_AGENT);
    float logP = -0.5f * LAMV * s2 + 0.5f * (float)(NCO * NFF) * logf(LAMV);
    float logQ = -0.5f * z2 + 0.5f * (float)NCO * ld;
    out[(size_t)NS * 147456 + smp] = logP - logQ;
  }
#undef GS
}

// ---------------------------------------------------------------- launch
extern "C" void kernel_launch(void* const* d_in, const int* in_sizes, int n_in,
                              void* d_out, int out_size, void* d_ws, size_t ws_size,
                              hipStream_t stream) {
  const float* X = (const float*)d_in[0];
  const float* u = (const float*)d_in[1];
  const float* lp = (const float*)d_in[2];
  const float* Z = (const float*)d_in[3];
  float* out = (float*)d_out;

  const size_t XU2 = 18874368;   // 1152*8192*2 (bf16), one s
  const size_t BM2 = 2097152;    // 128*8192*2
  const size_t FF4 = 5308416;    // 1152*1152*4
  const size_t FC4 = 589824;     // 1152*128*4
  const size_t FC = 147456;      // elems
  const size_t FF = 1327104;     // elems
  const size_t XSTR = 1048576;   // X elems per s

  int SB, kslices;
  if (ws_size >= ((size_t)206 << 20))      { SB = 8; kslices = 1; }
  else if (ws_size >= ((size_t)131 << 20)) { SB = 4; kslices = 2; }
  else                                     { SB = 2; kslices = 4; }

  char* ws = (char*)d_ws;
  size_t reg0 = (size_t)SB * XU2 + BM2;
  if (reg0 < 8 * FF4) reg0 = 8 * FF4;      // W aliases region0 after GEMMs
  unsigned short* Xu = (unsigned short*)ws;
  unsigned short* Bm = (unsigned short*)(ws + (size_t)SB * XU2);
  float* W = (float*)ws;
  size_t off = reg0;
  float* prec = (float*)(ws + off); off += 8 * FF4;
  float* XLY = (float*)(ws + off);  off += 8 * FC4;
  float* t1R = (float*)(ws + off);  off += 8 * FC4;   // also level-T scratch
  float* accum = (float*)(ws + off);
  unsigned* syncmem = (unsigned*)(ws + off + 512);    // regcnt/garr/go/slots

  k_build_B<<<4096, 256, 0, stream>>>(u, lp, Bm);
  hipMemsetAsync(accum, 0, 512 + 20480, stream);      // accum + sync region (per launch)
  if (kslices > 1) {
    hipMemsetAsync(prec, 0, 8 * FF4, stream);
    hipMemsetAsync(XLY, 0, 8 * FC4, stream);
    k_diag_init<<<dim3(5, 8), 256, 0, stream>>>(prec);
  }

  for (int pr = 0; pr < 8 / SB; ++pr) {
    k_build_Xu<<<36864, 256, 0, stream>>>(X + (size_t)pr * SB * XSTR, lp, Xu, SB);
    k_mfma<<<dim3(54, kslices, SB), 256, 0, stream>>>(Xu, Bm,
                                                      prec + (size_t)pr * SB * FF,
                                                      XLY + (size_t)pr * SB * FC,
                                                      8192 / kslices, kslices == 1 ? 1 : 0);
  }

  // fused: per-XCD sample pipelines (LDS-resident cholesky + inverse + apply + logpq)
  k_coop<<<COOPG, 256, 0, stream>>>(prec, W, XLY, t1R, Z, out, accum, syncmem);
}

// Round 9
// 1678.439 us; speedup vs baseline: 2.0083x; 1.0181x over previous
//
#include <hip/hip_runtime.h>
#include <hip/hip_bf16.h>
#include <math.h>

#define NS    8
#define NNI   32
#define NCI   128
#define NHH   16
#define NWW   16
#define NCO   128
#define NFF   1152
#define NLL   256
#define LAMV  1152.0f
#define COOPG 512

typedef short s8v __attribute__((ext_vector_type(8)));
typedef float f4v __attribute__((ext_vector_type(4)));

#define AS1 __attribute__((address_space(1)))
#define AS3 __attribute__((address_space(3)))

__device__ __forceinline__ float rdl(float v, int l) {
  return __uint_as_float(__builtin_amdgcn_readlane(__float_as_uint(v), (unsigned)l));
}

// ---------------------------------------------------------------- build Xu (bf16), z-loop inside
__global__ __launch_bounds__(256) void k_build_Xu(const float* __restrict__ X,
                                                  const float* __restrict__ lp,
                                                  unsigned short* __restrict__ Xu,
                                                  int nz) {
  unsigned idx = blockIdx.x * 256u + threadIdx.x;   // < 1152*8192
  unsigned m = idx & 8191u;
  unsigned f = idx >> 13;
  unsigned n = m >> 8, l = m & 255u, h = l >> 4, w = l & 15u;
  unsigned c = f / 9u, a = f - 9u * c;
  unsigned ki = a / 3u, kj = a - 3u * ki;
  int hi = (int)(h + ki) - 1, wi = (int)(w + kj) - 1;
  bool inb = (hi >= 0 && hi < NHH && wi >= 0 && wi < NWW);
  size_t xoff = (((size_t)n * NCI + c) << 8) + (size_t)(unsigned)(hi * NWW + wi);
  float spn = expf(0.5f * lp[n]);
  for (int z = 0; z < nz; ++z) {
    float v = inb ? X[(size_t)z * 1048576 + xoff] : 0.f;
    __hip_bfloat16 hv = __float2bfloat16(spn * v);
    Xu[(size_t)z * (NFF * 8192) + idx] = *(unsigned short*)&hv;
  }
}

__global__ __launch_bounds__(256) void k_build_B(const float* __restrict__ u,
                                                 const float* __restrict__ lp,
                                                 unsigned short* __restrict__ Bm) {
  unsigned idx = blockIdx.x * 256u + threadIdx.x;   // < 1,048,576
  unsigned m = idx & 8191u;
  unsigned c = idx >> 13;
  unsigned n = m >> 8, l = m & 255u;
  float spn = expf(0.5f * lp[n]);
  __hip_bfloat16 hv = __float2bfloat16(spn * u[((size_t)n * NCO + c) * NLL + l]);
  Bm[idx] = *(unsigned short*)&hv;
}

__global__ void k_diag_init(float* __restrict__ prec) {
  int s = blockIdx.y;
  int i = blockIdx.x * 256 + threadIdx.x;
  if (i < NFF) prec[(size_t)s * NFF * NFF + (size_t)i * NFF + i] = LAMV;
}

// ---------------------------------------------------------------- MFMA bf16 GEMM, SB s per launch
__global__ __launch_bounds__(256) void k_mfma(const unsigned short* __restrict__ XuBase,
                                              const unsigned short* __restrict__ Bm,
                                              float* __restrict__ prec,
                                              float* __restrict__ XLY,
                                              int kLen, int direct) {
  __shared__ unsigned short As[8192];
  __shared__ unsigned short Bs[8192];
  int z = blockIdx.z;
  const unsigned short* Xu = XuBase + (size_t)z * (NFF * 8192);
  prec += (size_t)z * NFF * NFF;
  XLY += (size_t)z * NFF * NCO;
  int bx = blockIdx.x;
  int row0, col0;
  const unsigned short* Ag;
  const unsigned short* Bg;
  bool isXLX;
  if (bx < 45) {
    int b = 0;
    while ((b + 1) * (b + 2) / 2 <= bx) b++;
    row0 = b * 128;
    col0 = (bx - b * (b + 1) / 2) * 128;
    Bg = Xu + (size_t)col0 * 8192;
    isXLX = true;
  } else {
    row0 = (bx - 45) * 128;
    col0 = 0;
    Bg = Bm;
    isXLX = false;
  }
  Ag = Xu + (size_t)row0 * 8192;

  int t = threadIdx.x;
  int lane = t & 63, w = t >> 6;
  int wm = w & 1, wn = w >> 1;
  int n16 = lane & 15, q = lane >> 4;
  int srow = lane >> 3, sch = lane & 7;

  f4v acc[4][4];
#pragma unroll
  for (int i = 0; i < 4; ++i)
#pragma unroll
    for (int j = 0; j < 4; ++j) acc[i][j] = (f4v)0.f;

  int kBase = blockIdx.y * kLen;
  for (int k0 = kBase; k0 < kBase + kLen; k0 += 64) {
    __syncthreads();
#pragma unroll
    for (int it = 0; it < 4; ++it) {
      int rA = (w * 4 + it) * 8 + srow;
      int cA = (sch - rA) & 7;
      const unsigned short* gpa = Ag + (size_t)rA * 8192 + k0 + cA * 8;
      const unsigned short* gpb = Bg + (size_t)rA * 8192 + k0 + cA * 8;
      __builtin_amdgcn_global_load_lds((AS1 const void*)gpa,
                                       (AS3 void*)&As[(w * 4 + it) * 512], 16, 0, 0);
      __builtin_amdgcn_global_load_lds((AS1 const void*)gpb,
                                       (AS3 void*)&Bs[(w * 4 + it) * 512], 16, 0, 0);
    }
    __syncthreads();
#pragma unroll
    for (int kk = 0; kk < 2; ++kk) {
      s8v af[4], bf[4];
#pragma unroll
      for (int im = 0; im < 4; ++im) {
        int r = wm * 64 + im * 16 + n16;
        int slot = ((kk * 4 + q) + r) & 7;
        af[im] = *(const s8v*)&As[r * 64 + slot * 8];
      }
#pragma unroll
      for (int in = 0; in < 4; ++in) {
        int r = wn * 64 + in * 16 + n16;
        int slot = ((kk * 4 + q) + r) & 7;
        bf[in] = *(const s8v*)&Bs[r * 64 + slot * 8];
      }
#pragma unroll
      for (int im = 0; im < 4; ++im)
#pragma unroll
        for (int in = 0; in < 4; ++in)
          acc[im][in] = __builtin_amdgcn_mfma_f32_16x16x32_bf16(af[im], bf[in], acc[im][in], 0, 0, 0);
    }
  }

#pragma unroll
  for (int im = 0; im < 4; ++im)
#pragma unroll
    for (int in = 0; in < 4; ++in) {
      int gr = row0 + wm * 64 + im * 16 + q * 4;
      int gc = (isXLX ? col0 : 0) + wn * 64 + in * 16 + n16;
      if (direct) {
        if (isXLX) {
#pragma unroll
          for (int tt = 0; tt < 4; ++tt)
            prec[(size_t)(gr + tt) * NFF + gc] =
                acc[im][in][tt] + ((gr + tt) == gc ? LAMV : 0.f);
        } else {
#pragma unroll
          for (int tt = 0; tt < 4; ++tt)
            XLY[(size_t)(gr + tt) * NCO + gc] = acc[im][in][tt];
        }
      } else {
        if (isXLX) {
#pragma unroll
          for (int tt = 0; tt < 4; ++tt)
            atomicAdd(&prec[(size_t)(gr + tt) * NFF + gc], acc[im][in][tt]);
        } else {
#pragma unroll
          for (int tt = 0; tt < 4; ++tt)
            atomicAdd(&XLY[(size_t)(gr + tt) * NCO + gc], acc[im][in][tt]);
        }
      }
    }
}

// ================================================================ persistent fused kernel
// Round-9 variable: ONE barrier per chol step (35 -> 18). Within a step, the only
// cross-block dependency is the factored diag(p): a per-step device-scope flag
// (release = vmcnt drain before flag store; acquire = spin + vL1 buffer_inv).
// Panel solver owns its column tile (trailed it locally), so no other cross-block dep.
__device__ __forceinline__ void xsync(unsigned* slot, unsigned* go, unsigned role,
                                      unsigned cnt, unsigned ep) {
  __syncthreads();   // drains vmcnt: all block stores are in the XCD's L2
  int t = threadIdx.x;
  if (t == 0)
    __hip_atomic_store(&slot[role], ep, __ATOMIC_RELAXED, __HIP_MEMORY_SCOPE_AGENT);
  if (role == 0) {
    if (t < 64) {
      for (;;) {
        unsigned ok = 1;
        for (unsigned i = (unsigned)t; i < cnt; i += 64u)
          ok &= (__hip_atomic_load(&slot[i], __ATOMIC_RELAXED, __HIP_MEMORY_SCOPE_AGENT) >= ep)
                    ? 1u : 0u;
        if (__all((int)ok)) break;
        __builtin_amdgcn_s_sleep(2);
      }
      if (t == 0)
        __hip_atomic_store(go, ep, __ATOMIC_RELAXED, __HIP_MEMORY_SCOPE_AGENT);
    }
  } else if (t == 0) {
    while (__hip_atomic_load(go, __ATOMIC_RELAXED, __HIP_MEMORY_SCOPE_AGENT) < ep)
      __builtin_amdgcn_s_sleep(2);
  }
  __syncthreads();
  asm volatile("buffer_inv" ::: "memory");   // vL1 invalidate (CU-local, cheap)
  __syncthreads();
}

// ---- factor 64x64 diag block from GLOBAL (fallback path, one wave)
__device__ void dev_fact64(float* D, float* accum_ld, int lane) {
  float x[64];
#pragma unroll
  for (int k = 0; k < 64; ++k) x[k] = D[(size_t)lane * NFF + k];
  float ld = 0.f;
#pragma unroll
  for (int k = 0; k < 64; ++k) {
    float dk = sqrtf(rdl(x[k], k));
    float inv = 1.0f / dk;
    ld += logf(dk);
    x[k] = (lane == k) ? dk : ((lane > k) ? x[k] * inv : x[k]);
#pragma unroll
    for (int kk = k + 1; kk < 64; ++kk)
      x[kk] = fmaf(-x[k], rdl(x[k], kk), x[kk]);
  }
  if (lane == 0) atomicAdd(accum_ld, 2.f * ld);
#pragma unroll
  for (int k = 0; k < 64; ++k) D[(size_t)lane * NFF + k] = x[k];
}

// ---- factor 64x64 diag block from LDS tile [64][68]; write result to global diag row
__device__ void dev_factLds(const float* T68, float* Dg, float* accum_ld, int lane) {
  float x[64];
#pragma unroll
  for (int k = 0; k < 64; ++k) x[k] = T68[lane * 68 + k];
  float ld = 0.f;
#pragma unroll
  for (int k = 0; k < 64; ++k) {
    float dk = sqrtf(rdl(x[k], k));
    float inv = 1.0f / dk;
    ld += logf(dk);
    x[k] = (lane == k) ? dk : ((lane > k) ? x[k] * inv : x[k]);
#pragma unroll
    for (int kk = k + 1; kk < 64; ++kk)
      x[kk] = fmaf(-x[k], rdl(x[k], kk), x[kk]);
  }
  if (lane == 0) atomicAdd(accum_ld, 2.f * ld);
#pragma unroll
  for (int k = 0; k < 64; ++k) Dg[(size_t)lane * NFF + k] = x[k];
}

// ---- panel solve X * L_pp^T = A(i,p) from LDS tile; write transposed-upper (p,i).
__device__ void dev_panelLds(const float* T68, const float* Dg, float* At, int lane) {
  float Lc[64];
#pragma unroll
  for (int k = 0; k < 64; ++k) Lc[k] = Dg[(size_t)k * NFF + lane];
  float x[64];
#pragma unroll
  for (int k = 0; k < 64; ++k) x[k] = T68[lane * 68 + k];
#pragma unroll
  for (int j = 0; j < 64; ++j) {
    float xj = x[j] / rdl(Lc[j], j);
    x[j] = xj;
#pragma unroll
    for (int k = j + 1; k < 64; ++k)
      x[k] = fmaf(-xj, rdl(Lc[k], j), x[k]);
  }
#pragma unroll
  for (int r = 0; r < 64; ++r) At[(size_t)r * NFF + lane] = x[r];
}

// ---- panel solve from GLOBAL tile (fallback for non-LDS-resident tiles)
__device__ void dev_panelGlb(const float* AiG, const float* Dg, float* At, int lane) {
  float Lc[64];
#pragma unroll
  for (int k = 0; k < 64; ++k) Lc[k] = Dg[(size_t)k * NFF + lane];
  float x[64];
#pragma unroll
  for (int k = 0; k < 64; ++k) x[k] = AiG[(size_t)lane * NFF + k];
#pragma unroll
  for (int j = 0; j < 64; ++j) {
    float xj = x[j] / rdl(Lc[j], j);
    x[j] = xj;
#pragma unroll
    for (int k = j + 1; k < 64; ++k)
      x[k] = fmaf(-xj, rdl(Lc[k], j), x[k]);
  }
#pragma unroll
  for (int r = 0; r < 64; ++r) At[(size_t)r * NFF + lane] = x[r];
}

// ---- trailing update C(i,j) -= P_i P_j^T (16-row chunk staging; LDS or global dest)
__device__ void dev_trail2(float* Ps, float* tileT, int p, int i, int j, float* csm) {
  const float* Ui = Ps + (size_t)(p * 64) * NFF + i * 64;
  const float* Uj = Ps + (size_t)(p * 64) * NFF + j * 64;
  float (*Ak)[68] = (float(*)[68])csm;
  float (*Bk)[68] = (float(*)[68])(csm + 1088);
  int t = threadIdx.x, tx = t & 15, ty = t >> 4;
  float acc[4][4];
#pragma unroll
  for (int a = 0; a < 4; ++a)
#pragma unroll
    for (int b2 = 0; b2 < 4; ++b2) acc[a][b2] = 0.f;
  for (int k0 = 0; k0 < 64; k0 += 16) {
    float4 a = *(const float4*)(Ui + (size_t)(k0 + ty) * NFF + tx * 4);
    float4 b = *(const float4*)(Uj + (size_t)(k0 + ty) * NFF + tx * 4);
    __syncthreads();
    *(float4*)&Ak[ty][tx * 4] = a;
    *(float4*)&Bk[ty][tx * 4] = b;
    __syncthreads();
#pragma unroll
    for (int kk = 0; kk < 16; ++kk) {
      float av[4], bv[4];
      *(float4*)&av[0] = *(const float4*)&Ak[kk][ty * 4];
      *(float4*)&bv[0] = *(const float4*)&Bk[kk][tx * 4];
#pragma unroll
      for (int a2 = 0; a2 < 4; ++a2)
#pragma unroll
        for (int b2 = 0; b2 < 4; ++b2) acc[a2][b2] = fmaf(av[a2], bv[b2], acc[a2][b2]);
    }
  }
  if (tileT) {
#pragma unroll
    for (int a = 0; a < 4; ++a) {
      float4* cp = (float4*)&tileT[(ty * 4 + a) * 68 + tx * 4];
      float4 cv = *cp;
      cv.x -= acc[a][0]; cv.y -= acc[a][1]; cv.z -= acc[a][2]; cv.w -= acc[a][3];
      *cp = cv;
    }
  } else {
    float* Cb = Ps + (size_t)(i * 64) * NFF + j * 64;
#pragma unroll
    for (int a = 0; a < 4; ++a) {
      float4* cp = (float4*)(Cb + (size_t)(ty * 4 + a) * NFF + tx * 4);
      float4 cv = *cp;
      cv.x -= acc[a][0]; cv.y -= acc[a][1]; cv.z -= acc[a][2]; cv.w -= acc[a][3];
      *cp = cv;
    }
  }
}

// ---- inverse of diag block (one wave): lane j holds column j of Linv
__device__ void dev_invdiag(const float* Ps, float* Ws, int lane) {
  float Lr[64];
#pragma unroll
  for (int m = 0; m < 64; ++m) Lr[m] = Ps[(size_t)lane * NFF + m];
  float x[64];
#pragma unroll
  for (int k = 0; k < 64; ++k) {
    float v = (lane == k) ? 1.f : 0.f;
#pragma unroll
    for (int m = 0; m < k; ++m)
      v = fmaf(-rdl(Lr[m], k), x[m], v);
    x[k] = v / rdl(Lr[k], k);
  }
#pragma unroll
  for (int k = 0; k < 64; ++k) Ws[(size_t)k * NFF + lane] = x[k];
}

// ---- level-1 pair inverse: W[2p+1][2p] = -D2 * L21 * D1
__device__ void dev_inv1(const float* Ps, float* Ws, int p, float* sm) {
  int J = 2 * p, I = 2 * p + 1;
  float (*Ak)[65] = (float(*)[65])sm;
  float (*Bk)[65] = (float(*)[65])(sm + 4160);
  float (*Dk)[65] = (float(*)[65])(sm + 8320);
  float (*Tt)[65] = (float(*)[65])(sm + 12480);
  int t = threadIdx.x, tx = t & 15, ty = t >> 4;
  __syncthreads();
  for (int e = t; e < 4096; e += 256) {
    int r = e >> 6, cc = e & 63;
    Ak[r][cc] = Ps[(size_t)(J * 64 + r) * NFF + I * 64 + cc];
    Bk[r][cc] = Ws[(size_t)(J * 64 + r) * NFF + J * 64 + cc];
  }
  {
    int i = t >> 2;
#pragma unroll
    for (int it = 0; it < 4; ++it) {
      int kq = (t & 3) * 4 + it * 16;
      float4 a = *(const float4*)&Ws[(size_t)(I * 64 + i) * NFF + I * 64 + kq];
      Dk[kq + 0][i] = a.x; Dk[kq + 1][i] = a.y; Dk[kq + 2][i] = a.z; Dk[kq + 3][i] = a.w;
    }
  }
  __syncthreads();
  float acc[4][4];
#pragma unroll
  for (int a = 0; a < 4; ++a)
#pragma unroll
    for (int b = 0; b < 4; ++b) acc[a][b] = 0.f;
#pragma unroll 8
  for (int kk = 0; kk < 64; ++kk) {
    float av[4], bv[4];
#pragma unroll
    for (int a = 0; a < 4; ++a) av[a] = Ak[kk][ty * 4 + a];
#pragma unroll
    for (int b = 0; b < 4; ++b) bv[b] = Bk[kk][tx * 4 + b];
#pragma unroll
    for (int a = 0; a < 4; ++a)
#pragma unroll
      for (int b = 0; b < 4; ++b) acc[a][b] = fmaf(av[a], bv[b], acc[a][b]);
  }
#pragma unroll
  for (int a = 0; a < 4; ++a)
#pragma unroll
    for (int b = 0; b < 4; ++b) Tt[ty * 4 + a][tx * 4 + b] = acc[a][b];
  __syncthreads();
  float a2[4][4];
#pragma unroll
  for (int a = 0; a < 4; ++a)
#pragma unroll
    for (int b = 0; b < 4; ++b) a2[a][b] = 0.f;
#pragma unroll 8
  for (int kk = 0; kk < 64; ++kk) {
    float av[4], bv[4];
#pragma unroll
    for (int a = 0; a < 4; ++a) av[a] = Dk[kk][ty * 4 + a];
#pragma unroll
    for (int b = 0; b < 4; ++b) bv[b] = Tt[kk][tx * 4 + b];
#pragma unroll
    for (int a = 0; a < 4; ++a)
#pragma unroll
      for (int b = 0; b < 4; ++b) a2[a][b] = fmaf(av[a], bv[b], a2[a][b]);
  }
#pragma unroll
  for (int a = 0; a < 4; ++a) {
    float4 o;
    o.x = -a2[a][0]; o.y = -a2[a][1]; o.z = -a2[a][2]; o.w = -a2[a][3];
    *(float4*)&Ws[(size_t)(I * 64 + ty * 4 + a) * NFF + J * 64 + tx * 4] = o;
  }
}

// ---- level kernel A: T = L21 * W11 (tile r, col-block c)
__device__ void dev_invA(const float* Ps, const float* Ws, float* Tbs,
                         int n1, int n2, int nc, int c0, int r, int ccb, int pq,
                         float* sm) {
  int ldT = nc * 64;
  int o = pq * 2 * n1;
  int I = o + n1 + r, c = c0 + ccb;
  float* Ts = Tbs + (size_t)pq * (size_t)(n2 * 64) * ldT;
  float (*Aks)[68] = (float(*)[68])sm;
  float (*Bks)[68] = (float(*)[68])(sm + 1088);
  int t = threadIdx.x, tx = t & 15, ty = t >> 4;
  float acc[4][4];
#pragma unroll
  for (int a = 0; a < 4; ++a)
#pragma unroll
    for (int b = 0; b < 4; ++b) acc[a][b] = 0.f;
  for (int kb = c; kb < n1; ++kb) {
    const float* up = Ps + (size_t)((o + kb) * 64) * NFF + I * 64;
    const float* wp = Ws + (size_t)((o + kb) * 64) * NFF + (o + c) * 64;
    for (int k0 = 0; k0 < 64; k0 += 16) {
      float4 a = *(const float4*)(up + (size_t)(k0 + ty) * NFF + tx * 4);
      float4 b = *(const float4*)(wp + (size_t)(k0 + ty) * NFF + tx * 4);
      __syncthreads();
      *(float4*)&Aks[ty][tx * 4] = a;
      *(float4*)&Bks[ty][tx * 4] = b;
      __syncthreads();
#pragma unroll
      for (int kk = 0; kk < 16; ++kk) {
        float av[4], bv[4];
        *(float4*)&av[0] = *(const float4*)&Aks[kk][ty * 4];
        *(float4*)&bv[0] = *(const float4*)&Bks[kk][tx * 4];
#pragma unroll
        for (int a2 = 0; a2 < 4; ++a2)
#pragma unroll
          for (int b2 = 0; b2 < 4; ++b2) acc[a2][b2] = fmaf(av[a2], bv[b2], acc[a2][b2]);
      }
    }
  }
#pragma unroll
  for (int a = 0; a < 4; ++a) {
    float4 v;
    v.x = acc[a][0]; v.y = acc[a][1]; v.z = acc[a][2]; v.w = acc[a][3];
    *(float4*)(Ts + (size_t)(r * 64 + ty * 4 + a) * ldT + ccb * 64 + tx * 4) = v;
  }
}

// ---- level kernel B: W21 = -W22 * T
__device__ void dev_invB(float* Ws, const float* Tbs,
                         int n1, int n2, int nc, int c0, int r, int ccb, int pq,
                         float* sm) {
  int ldT = nc * 64;
  int o = pq * 2 * n1;
  int I = o + n1 + r, c = c0 + ccb;
  const float* Ts = Tbs + (size_t)pq * (size_t)(n2 * 64) * ldT;
  float (*Aks)[68] = (float(*)[68])sm;
  float (*Bks)[68] = (float(*)[68])(sm + 1088);
  int t = threadIdx.x, tx = t & 15, ty = t >> 4;
  float acc[4][4];
#pragma unroll
  for (int a = 0; a < 4; ++a)
#pragma unroll
    for (int b = 0; b < 4; ++b) acc[a][b] = 0.f;
  for (int kb = 0; kb <= r; ++kb) {
    const float* ap = Ws + (size_t)(I * 64) * NFF + (o + n1 + kb) * 64;
    const float* tp = Ts + (size_t)(kb * 64) * ldT + ccb * 64;
    for (int k0 = 0; k0 < 64; k0 += 16) {
      float4 a = *(const float4*)(ap + (size_t)(t >> 2) * NFF + k0 + (t & 3) * 4);
      float4 b = *(const float4*)(tp + (size_t)(k0 + ty) * ldT + tx * 4);
      __syncthreads();
      Aks[(t & 3) * 4 + 0][t >> 2] = a.x;
      Aks[(t & 3) * 4 + 1][t >> 2] = a.y;
      Aks[(t & 3) * 4 + 2][t >> 2] = a.z;
      Aks[(t & 3) * 4 + 3][t >> 2] = a.w;
      *(float4*)&Bks[ty][tx * 4] = b;
      __syncthreads();
#pragma unroll
      for (int kk = 0; kk < 16; ++kk) {
        float av[4], bv[4];
        *(float4*)&av[0] = *(const float4*)&Aks[kk][ty * 4];
        *(float4*)&bv[0] = *(const float4*)&Bks[kk][tx * 4];
#pragma unroll
        for (int a2 = 0; a2 < 4; ++a2)
#pragma unroll
          for (int b2 = 0; b2 < 4; ++b2) acc[a2][b2] = fmaf(av[a2], bv[b2], acc[a2][b2]);
      }
    }
  }
#pragma unroll
  for (int a = 0; a < 4; ++a) {
    float4 v;
    v.x = -acc[a][0]; v.y = -acc[a][1]; v.z = -acc[a][2]; v.w = -acc[a][3];
    *(float4*)&Ws[(size_t)(I * 64 + ty * 4 + a) * NFF + (o + c) * 64 + tx * 4] = v;
  }
}

// ---- apply 1: t1R = W*XLY + Z (+ sum Z^2)
__device__ void dev_app1(const float* Ws, const float* Ys, const float* Zs,
                         float* Os, float* accum, int rb, int ch, int s, float* sm) {
  int r0 = rb * 64, c0 = ch * 64;
  float (*As_)[68] = (float(*)[68])sm;
  float (*Bs_)[68] = (float(*)[68])(sm + 1088);
  float* red = sm + 2176;
  int t = threadIdx.x, tx = t & 15, ty = t >> 4;
  float acc[4][4];
#pragma unroll
  for (int a = 0; a < 4; ++a)
#pragma unroll
    for (int b = 0; b < 4; ++b) acc[a][b] = 0.f;
  int kmax = r0 + 64;
  for (int k0 = 0; k0 < kmax; k0 += 16) {
    float4 a = *(const float4*)(Ws + (size_t)(r0 + (t >> 2)) * NFF + k0 + (t & 3) * 4);
    float4 bb = *(const float4*)(Ys + (size_t)(k0 + (t >> 4)) * NCO + c0 + (t & 15) * 4);
    __syncthreads();
    As_[(t & 3) * 4 + 0][t >> 2] = a.x; As_[(t & 3) * 4 + 1][t >> 2] = a.y;
    As_[(t & 3) * 4 + 2][t >> 2] = a.z; As_[(t & 3) * 4 + 3][t >> 2] = a.w;
    *(float4*)&Bs_[t >> 4][(t & 15) * 4] = bb;
    __syncthreads();
#pragma unroll
    for (int kk = 0; kk < 16; ++kk) {
      float av[4], bv[4];
      *(float4*)&av[0] = *(const float4*)&As_[kk][ty * 4];
      *(float4*)&bv[0] = *(const float4*)&Bs_[kk][tx * 4];
#pragma unroll
      for (int a2 = 0; a2 < 4; ++a2)
#pragma unroll
        for (int b2 = 0; b2 < 4; ++b2) acc[a2][b2] = fmaf(av[a2], bv[b2], acc[a2][b2]);
    }
  }
  float z2 = 0.f;
#pragma unroll
  for (int a2 = 0; a2 < 4; ++a2) {
    int row = r0 + ty * 4 + a2;
    const float* zp = Zs + (size_t)row * NCO + c0 + tx * 4;
    float* op = Os + (size_t)row * NCO + c0 + tx * 4;
    float4 z0 = *(const float4*)zp;
    float4 v0;
    v0.x = acc[a2][0] + z0.x; v0.y = acc[a2][1] + z0.y;
    v0.z = acc[a2][2] + z0.z; v0.w = acc[a2][3] + z0.w;
    z2 += z0.x * z0.x + z0.y * z0.y + z0.z * z0.z + z0.w * z0.w;
    *(float4*)op = v0;
  }
  __syncthreads();
  red[t] = z2;
  __syncthreads();
  for (int o = 128; o > 0; o >>= 1) {
    if (t < o) red[t] += red[t + o];
    __syncthreads();
  }
  if (t == 0) atomicAdd(&accum[s * 4 + 1], red[0]);
}

// ---- apply 2: sample = W^T * t1R (+ sum S^2)
__device__ void dev_app2(const float* Ws, const float* Rs, float* Op,
                         float* accum, int rb, int ch, int s, float* sm) {
  int r0 = rb * 64, c0 = ch * 64;
  float (*As_)[68] = (float(*)[68])sm;
  float (*Bs_)[68] = (float(*)[68])(sm + 1088);
  float* red = sm + 2176;
  int t = threadIdx.x, tx = t & 15, ty = t >> 4;
  float acc[4][4];
#pragma unroll
  for (int a = 0; a < 4; ++a)
#pragma unroll
    for (int b = 0; b < 4; ++b) acc[a][b] = 0.f;
  for (int k0 = r0; k0 < NFF; k0 += 16) {
    float4 a = *(const float4*)(Ws + (size_t)(k0 + (t >> 4)) * NFF + r0 + (t & 15) * 4);
    float4 bb = *(const float4*)(Rs + (size_t)(k0 + (t >> 4)) * NCO + c0 + (t & 15) * 4);
    __syncthreads();
    *(float4*)&As_[t >> 4][(t & 15) * 4] = a;
    *(float4*)&Bs_[t >> 4][(t & 15) * 4] = bb;
    __syncthreads();
#pragma unroll
    for (int kk = 0; kk < 16; ++kk) {
      float av[4], bv[4];
      *(float4*)&av[0] = *(const float4*)&As_[kk][ty * 4];
      *(float4*)&bv[0] = *(const float4*)&Bs_[kk][tx * 4];
#pragma unroll
      for (int a2 = 0; a2 < 4; ++a2)
#pragma unroll
        for (int b2 = 0; b2 < 4; ++b2) acc[a2][b2] = fmaf(av[a2], bv[b2], acc[a2][b2]);
    }
  }
  float s2 = 0.f;
#pragma unroll
  for (int b2 = 0; b2 < 4; ++b2) {
    int col = c0 + tx * 4 + b2;
    float4 v;
    v.x = acc[0][b2]; v.y = acc[1][b2]; v.z = acc[2][b2]; v.w = acc[3][b2];
    s2 += v.x * v.x + v.y * v.y + v.z * v.z + v.w * v.w;
    *(float4*)(Op + (size_t)col * NFF + r0 + ty * 4) = v;
  }
  __syncthreads();
  red[t] = s2;
  __syncthreads();
  for (int o = 128; o > 0; o >>= 1) {
    if (t < o) red[t] += red[t + o];
    __syncthreads();
  }
  if (t == 0) atomicAdd(&accum[s * 4 + 0], red[0]);
}

// ---- the fused persistent kernel: per-XCD sample pipelines, LDS-resident Cholesky
__global__ __launch_bounds__(256, 2) void k_coop(float* __restrict__ prec,
                                                 float* __restrict__ W,
                                                 const float* __restrict__ XLY,
                                                 float* __restrict__ t1R,
                                                 const float* __restrict__ Z,
                                                 float* __restrict__ out,
                                                 float* __restrict__ accum,
                                                 unsigned* __restrict__ syncmem) {
  // 66KB LDS: chol = 3 tiles [64][68] @ 0/4352/8704 + 2x[16][68] chunk scratch @ 13056.
  __shared__ float SM[16896];
  __shared__ unsigned shr[2];
  int t = threadIdx.x;
  int wv = t >> 6, lane = t & 63;

  // ---- registration: physical XCD id -> group; role within group
  unsigned xcd;
  asm("s_getreg_b32 %0, hwreg(HW_REG_XCC_ID)" : "=s"(xcd));
  xcd &= 7u;
  unsigned* regcnt = syncmem;              // [0..8)
  unsigned* garr = syncmem + 8;            // [8]
  unsigned* go = syncmem + 64 + xcd * 16;  // padded per-XCD go word
  unsigned* slot = syncmem + 256 + xcd * 512;
  unsigned* dflag = syncmem + 4352 + xcd * 32;  // per-step diag-ready flags (18 used)
  if (t == 0) {
    unsigned r = __hip_atomic_fetch_add(&regcnt[xcd], 1u,
                                        __ATOMIC_RELAXED, __HIP_MEMORY_SCOPE_AGENT);
    asm volatile("s_waitcnt vmcnt(0)" ::: "memory");   // regcnt RMW applied before arrive
    __hip_atomic_fetch_add(garr, 1u, __ATOMIC_RELAXED, __HIP_MEMORY_SCOPE_AGENT);
    while (__hip_atomic_load(garr, __ATOMIC_RELAXED, __HIP_MEMORY_SCOPE_AGENT) < gridDim.x)
      __builtin_amdgcn_s_sleep(8);
    shr[0] = r;
    shr[1] = __hip_atomic_load(&regcnt[xcd], __ATOMIC_RELAXED, __HIP_MEMORY_SCOPE_AGENT);
  }
  __syncthreads();
  unsigned role = shr[0], cnt = shr[1];

  int smp = (int)xcd;                       // sample pinned to this XCD
  float* Ps = prec + (size_t)smp * NFF * NFF;
  float* Wsb = W + (size_t)smp * NFF * NFF;
  const float* Ys = XLY + (size_t)smp * 147456;
  float* Rs = t1R + (size_t)smp * 147456;
  const float* Zs = Z + (size_t)smp * 147456;
  float* Outp = out + (size_t)smp * 147456;
  unsigned ep = 0;
#define GS() xsync(slot, go, role, cnt, ++ep)

  // ---- tile ownership: tile tt = i(i+1)/2+j (171 tiles), owner = tt % cnt, slot = tt / cnt
  int ti[3], tj[3];
  bool tv[3];
#pragma unroll
  for (int sl = 0; sl < 3; ++sl) {
    unsigned tt = role + (unsigned)sl * cnt;
    tv[sl] = (tt < 171u);
    ti[sl] = 0; tj[sl] = 0;
    if (tv[sl]) {
      int i = 0;
      while ((unsigned)((i + 1) * (i + 2) / 2) <= tt) ++i;
      ti[sl] = i;
      tj[sl] = (int)tt - i * (i + 1) / 2;
    }
  }

  // ---- load owned tiles global -> LDS
#pragma unroll
  for (int sl = 0; sl < 3; ++sl)
    if (tv[sl]) {
      const float* Gb = Ps + (size_t)(ti[sl] * 64) * NFF + tj[sl] * 64;
      float* T = SM + sl * 4352;
      for (int e = t; e < 1024; e += 256) {
        int r = e >> 4, c4 = (e & 15) * 4;
        *(float4*)&T[r * 68 + c4] = *(const float4*)(Gb + (size_t)r * NFF + c4);
      }
    }
  __syncthreads();

  // ---- merged cholesky: one phase per step p = 0..17
  // phase body: (a0) diag owner trails (p,p) for step p-1, factors, flags;
  //             (a1) other owned trails for step p-1; sync;
  //             (c) panel waves spin flag -> solve -> write upper; barrier.
  for (int p = 0; p <= 17; ++p) {
    // (a0) diag owner path (at most one block per sample matches; guards block-uniform)
#pragma unroll
    for (int sl = 0; sl < 3; ++sl)
      if (tv[sl] && ti[sl] == p && tj[sl] == p) {
        if (p > 0) dev_trail2(Ps, SM + sl * 4352, p - 1, p, p, SM + 13056);
        __syncthreads();
        if (t < 64)
          dev_factLds(SM + sl * 4352, Ps + (size_t)(p * 64) * NFF + p * 64,
                      &accum[smp * 4 + 2], t);
        if (t == 0) {
          asm volatile("s_waitcnt vmcnt(0)" ::: "memory");   // Dg stores drained to L2
          __hip_atomic_store(&dflag[p], 1u, __ATOMIC_RELAXED, __HIP_MEMORY_SCOPE_AGENT);
        }
      }
    if (cnt < 57u) {
      unsigned td = (unsigned)(p * (p + 1) / 2 + p);
      if (td % cnt == role && td / cnt >= 3u) {
        if (p > 0) dev_trail2(Ps, nullptr, p - 1, p, p, SM + 13056);
        __syncthreads();
        asm volatile("buffer_inv" ::: "memory");   // re-read own RMW'd lines from L2
        if (t < 64)
          dev_fact64(Ps + (size_t)(p * 64) * NFF + p * 64, &accum[smp * 4 + 2], t);
        if (t == 0) {
          asm volatile("s_waitcnt vmcnt(0)" ::: "memory");
          __hip_atomic_store(&dflag[p], 1u, __ATOMIC_RELAXED, __HIP_MEMORY_SCOPE_AGENT);
        }
      }
    }
    // (a1) other owned trails for step p-1
    if (p > 0) {
#pragma unroll
      for (int sl = 0; sl < 3; ++sl)
        if (tv[sl] && ti[sl] >= p && tj[sl] >= p && !(ti[sl] == p && tj[sl] == p))
          dev_trail2(Ps, SM + sl * 4352, p - 1, ti[sl], tj[sl], SM + 13056);
      if (cnt < 57u) {
        for (unsigned tt = role + 3u * cnt; tt < 171u; tt += cnt) {
          int i = 0;
          while ((unsigned)((i + 1) * (i + 2) / 2) <= tt) ++i;
          int j = (int)tt - i * (i + 1) / 2;
          if (i >= p && j >= p && !(i == p && j == p))
            dev_trail2(Ps, nullptr, p - 1, i, j, SM + 13056);
        }
      }
    }
    __syncthreads();   // LDS tile updates visible to the panel-solving wave
    // (c) panels(p): owners of (i,p), i>p — wave-level, gated by the diag flag
    if (p < 17) {
#pragma unroll
      for (int sl = 0; sl < 3; ++sl)
        if (wv == sl && tv[sl] && tj[sl] == p && ti[sl] > p) {
          while (__hip_atomic_load(&dflag[p], __ATOMIC_RELAXED,
                                   __HIP_MEMORY_SCOPE_AGENT) == 0u)
            __builtin_amdgcn_s_sleep(1);
          asm volatile("buffer_inv" ::: "memory");   // fresh Dg from L2
          dev_panelLds(SM + sl * 4352, Ps + (size_t)(p * 64) * NFF + p * 64,
                       Ps + (size_t)(p * 64) * NFF + ti[sl] * 64, lane);
        }
      if (cnt < 57u && wv == 3) {
        for (unsigned tt = role + 3u * cnt; tt < 171u; tt += cnt) {
          int i = 0;
          while ((unsigned)((i + 1) * (i + 2) / 2) <= tt) ++i;
          int j = (int)tt - i * (i + 1) / 2;
          if (j == p && i > p) {
            while (__hip_atomic_load(&dflag[p], __ATOMIC_RELAXED,
                                     __HIP_MEMORY_SCOPE_AGENT) == 0u)
              __builtin_amdgcn_s_sleep(1);
            asm volatile("buffer_inv" ::: "memory");
            dev_panelGlb(Ps + (size_t)(i * 64) * NFF + p * 64,
                         Ps + (size_t)(p * 64) * NFF + p * 64,
                         Ps + (size_t)(p * 64) * NFF + i * 64, lane);
          }
        }
      }
    }
    GS();
  }

  // ---- inverse diag blocks (18 wave tasks per sample)
  for (unsigned tau = role * 4 + wv; tau < 18u; tau += cnt * 4) {
    const float* Pd = Ps + (size_t)(tau * 64) * NFF + tau * 64;
    float* Wd = Wsb + (size_t)(tau * 64) * NFF + tau * 64;
    dev_invdiag(Pd, Wd, lane);
  }
  GS();

  // ---- level-1 pair inverse (9 block tasks per sample)
  for (unsigned tau = role; tau < 9u; tau += cnt)
    dev_inv1(Ps, Wsb, (int)tau, SM);
  GS();

  // ---- recursive block-doubling levels: (n1, n2, nc, c0), npairs
  {
    const int LV[5][4] = { {2, 2, 2, 0}, {4, 4, 4, 0},
                           {8, 8, 4, 0}, {8, 8, 4, 4}, {16, 2, 16, 0} };
    const int NP[5] = {4, 2, 1, 1, 1};
    for (int lv = 0; lv < 5; ++lv) {
      int n1 = LV[lv][0], n2 = LV[lv][1], nc = LV[lv][2], c0 = LV[lv][3], np = NP[lv];
      unsigned ntask = (unsigned)(n2 * nc * np);
      for (unsigned tau = role; tau < ntask; tau += cnt) {
        unsigned q = tau;
        int r = (int)(q % (unsigned)n2); q /= (unsigned)n2;
        int ccb = (int)(q % (unsigned)nc); int pq = (int)(q / (unsigned)nc);
        dev_invA(Ps, Wsb, Rs, n1, n2, nc, c0, r, ccb, pq, SM);
      }
      GS();
      for (unsigned tau = role; tau < ntask; tau += cnt) {
        unsigned q = tau;
        int r = (int)(q % (unsigned)n2); q /= (unsigned)n2;
        int ccb = (int)(q % (unsigned)nc); int pq = (int)(q / (unsigned)nc);
        dev_invB(Wsb, Rs, n1, n2, nc, c0, r, ccb, pq, SM);
      }
      GS();
    }
  }

  // ---- apply 1 (36 block tasks per sample)
  for (unsigned tau = role; tau < 36u; tau += cnt) {
    int ch = (int)(tau & 1u), rb = (int)(tau >> 1);
    dev_app1(Wsb, Ys, Zs, Rs, accum, rb, ch, smp, SM);
  }
  GS();
  // ---- apply 2 (36 block tasks per sample)
  for (unsigned tau = role; tau < 36u; tau += cnt) {
    int ch = (int)(tau & 1u), rb = (int)(tau >> 1);
    dev_app2(Wsb, Rs, Outp, accum, rb, ch, smp, SM);
  }
  GS();
  // ---- final logpq (per-sample, by its XCD's role-0 block)
  if (role == 0 && t == 0) {
    float s2 = __hip_atomic_load(&accum[smp * 4 + 0], __ATOMIC_RELAXED, __HIP_MEMORY_SCOPE_AGENT);
    float z2 = __hip_atomic_load(&accum[smp * 4 + 1], __ATOMIC_RELAXED, __HIP_MEMORY_SCOPE_AGENT);
    float ld = __hip_atomic_load(&accum[smp * 4 + 2], __ATOMIC_RELAXED, __HIP_MEMORY_SCOPE_AGENT);
    float logP = -0.5f * LAMV * s2 + 0.5f * (float)(NCO * NFF) * logf(LAMV);
    float logQ = -0.5f * z2 + 0.5f * (float)NCO * ld;
    out[(size_t)NS * 147456 + smp] = logP - logQ;
  }
#undef GS
}

// ---------------------------------------------------------------- launch
extern "C" void kernel_launch(void* const* d_in, const int* in_sizes, int n_in,
                              void* d_out, int out_size, void* d_ws, size_t ws_size,
                              hipStream_t stream) {
  const float* X = (const float*)d_in[0];
  const float* u = (const float*)d_in[1];
  const float* lp = (const float*)d_in[2];
  const float* Z = (const float*)d_in[3];
  float* out = (float*)d_out;

  const size_t XU2 = 18874368;   // 1152*8192*2 (bf16), one s
  const size_t BM2 = 2097152;    // 128*8192*2
  const size_t FF4 = 5308416;    // 1152*1152*4
  const size_t FC4 = 589824;     // 1152*128*4
  const size_t FC = 147456;      // elems
  const size_t FF = 1327104;     // elems
  const size_t XSTR = 1048576;   // X elems per s

  int SB, kslices;
  if (ws_size >= ((size_t)206 << 20))      { SB = 8; kslices = 1; }
  else if (ws_size >= ((size_t)131 << 20)) { SB = 4; kslices = 2; }
  else                                     { SB = 2; kslices = 4; }

  char* ws = (char*)d_ws;
  size_t reg0 = (size_t)SB * XU2 + BM2;
  if (reg0 < 8 * FF4) reg0 = 8 * FF4;      // W aliases region0 after GEMMs
  unsigned short* Xu = (unsigned short*)ws;
  unsigned short* Bm = (unsigned short*)(ws + (size_t)SB * XU2);
  float* W = (float*)ws;
  size_t off = reg0;
  float* prec = (float*)(ws + off); off += 8 * FF4;
  float* XLY = (float*)(ws + off);  off += 8 * FC4;
  float* t1R = (float*)(ws + off);  off += 8 * FC4;   // also level-T scratch
  float* accum = (float*)(ws + off);
  unsigned* syncmem = (unsigned*)(ws + off + 512);    // regcnt/garr/go/slots/dflags

  k_build_B<<<4096, 256, 0, stream>>>(u, lp, Bm);
  hipMemsetAsync(accum, 0, 512 + 20480, stream);      // accum + sync region (per launch)
  if (kslices > 1) {
    hipMemsetAsync(prec, 0, 8 * FF4, stream);
    hipMemsetAsync(XLY, 0, 8 * FC4, stream);
    k_diag_init<<<dim3(5, 8), 256, 0, stream>>>(prec);
  }

  for (int pr = 0; pr < 8 / SB; ++pr) {
    k_build_Xu<<<36864, 256, 0, stream>>>(X + (size_t)pr * SB * XSTR, lp, Xu, SB);
    k_mfma<<<dim3(54, kslices, SB), 256, 0, stream>>>(Xu, Bm,
                                                      prec + (size_t)pr * SB * FF,
                                                      XLY + (size_t)pr * SB * FC,
                                                      8192 / kslices, kslices == 1 ? 1 : 0);
  }

  // fused: per-XCD sample pipelines (merged-phase LDS cholesky + inverse + apply + logpq)
  k_coop<<<COOPG, 256, 0, stream>>>(prec, W, XLY, t1R, Z, out, accum, syncmem);
}